// Round 2
// baseline (449.107 us; speedup 1.0000x reference)
//
#include <hip/hip_runtime.h>

typedef _Float16 f16;
typedef f16   f16x8 __attribute__((ext_vector_type(8)));
typedef float f32x4 __attribute__((ext_vector_type(4)));
typedef unsigned int uint;

#define NB     65536
#define NROWS  (NB*6)

// ---- weight-fragment array layout inside d_ws (f16 element offsets) ----
// frag linear index: ((kc*8 + nt)*64 + lane)*8 + j  ;  k = kc*32 + (lane>>4)*8 + j ; n = nt*16 + (lane&15)
#define OFF_E1 0        // e_w1 24x128 padded to 32x128 : 1 kc  -> 4096 f16
#define OFF_E2 4096     // e_w2 128x128 : 4 kc -> 16384
#define OFF_V1 20480
#define OFF_V2 36864
#define OFF_A1 53248    // a_w1 256x128 : 8 kc -> 32768  (kc0-3 = emb part, kc4-7 = mean part)
#define OFF_A2 86016
#define WFRAG_TOTAL 102400

#define EMB_BYTE_OFF   204800ull                       // NROWS x 128 f16 = 100663296 B
#define MEAN_BYTE_OFF  (204800ull + 100663296ull)      // NB x 128 f16   = 16777216 B

#define LDS_FENCE() asm volatile("s_waitcnt lgkmcnt(0)" ::: "memory")

__device__ __forceinline__ float tanh_fast(float x) {
  // tanh(x) = 1 - 2/(e^{2x}+1) ; saturates correctly at +/-inf, no NaN
  float e = __expf(2.0f * x);
  return 1.0f - 2.0f * __builtin_amdgcn_rcpf(e + 1.0f);
}

// ---------------- prep: f32 weights -> f16 fragment order ----------------
__global__ void prep_weights(const float* __restrict__ e1, const float* __restrict__ e2,
                             const float* __restrict__ v1, const float* __restrict__ v2,
                             const float* __restrict__ a1, const float* __restrict__ a2,
                             f16* __restrict__ dst)
{
  int i = blockIdx.x * 256 + threadIdx.x;
  if (i >= WFRAG_TOTAL) return;
  const float* src; int base, Ksrc;
  if      (i < OFF_E2) { src = e1; base = OFF_E1; Ksrc = 24;  }
  else if (i < OFF_V1) { src = e2; base = OFF_E2; Ksrc = 128; }
  else if (i < OFF_V2) { src = v1; base = OFF_V1; Ksrc = 128; }
  else if (i < OFF_A1) { src = v2; base = OFF_V2; Ksrc = 128; }
  else if (i < OFF_A2) { src = a1; base = OFF_A1; Ksrc = 256; }
  else                 { src = a2; base = OFF_A2; Ksrc = 128; }
  int li   = i - base;
  int j    = li & 7;
  int lane = (li >> 3) & 63;
  int nt   = (li >> 9) & 7;
  int kc   = li >> 12;
  int k = kc*32 + (lane >> 4)*8 + j;
  int n = nt*16 + (lane & 15);
  float v = (k < Ksrc) ? src[k*128 + n] : 0.0f;
  dst[i] = (f16)v;
}

// ---------------- shared device helpers ----------------
__device__ __forceinline__ void mfma_layer(f32x4* acc, const f16x8* afrag, const f16* W,
                                           int lane, int nkc)
{
  #pragma unroll
  for (int kc = 0; kc < nkc; ++kc) {
    #pragma unroll
    for (int nt = 0; nt < 8; ++nt) {
      f16x8 wf = *(const f16x8*)(W + (((kc*8 + nt)*64) + lane)*8);
      acc[nt] = __builtin_amdgcn_mfma_f32_16x16x32_f16(afrag[kc], wf, acc[nt], 0, 0, 0);
    }
  }
}

// tanh(acc+bias) -> swizzled f16 tile rows [wid*16, wid*16+16)
__device__ __forceinline__ void write_h_tile(char* tbuf, const f32x4* acc, const float* bias,
                                             int wid, int lane)
{
  int col0 = lane & 15, q = lane >> 4;
  #pragma unroll
  for (int nt = 0; nt < 8; ++nt) {
    int col = nt*16 + col0;
    float b = bias[col];
    #pragma unroll
    for (int rg = 0; rg < 4; ++rg) {
      int row = wid*16 + q*4 + rg;          // C/D: row=(lane>>4)*4+reg (m89-verified)
      float h = tanh_fast(acc[nt][rg] + b);
      int byte = (row*256 + col*2) ^ ((row & 7) << 4);
      *(f16*)(tbuf + byte) = (f16)h;
    }
  }
}

__device__ __forceinline__ void read_h_frags(const char* tbuf, f16x8* frag, int wid, int lane)
{
  int c = lane >> 4, rr = lane & 15;
  int row = wid*16 + rr;                    // A frag: row = lane&15, k = (lane>>4)*8+j
  #pragma unroll
  for (int kc = 0; kc < 4; ++kc) {
    int byte = (row*256 + kc*64 + c*16) ^ ((row & 7) << 4);
    frag[kc] = *(const f16x8*)(tbuf + byte);
  }
}

// ---------------- kernel A: encoder MLP -> emb, emb_mean ----------------
__global__ void __launch_bounds__(384, 2) enc_kernel(
  const float* __restrict__ self_obs, const float* __restrict__ obs,
  const float* __restrict__ e_b1, const float* __restrict__ e_b2,
  const f16* __restrict__ wfrag_g, f16* __restrict__ emb_out, f16* __restrict__ mean_out)
{
  __shared__ __align__(16) f16 wE1[4096];
  __shared__ __align__(16) f16 wE2[16384];
  __shared__ __align__(16) char tbuf[24576];   // 96 x 128 f16, XOR-swizzled
  __shared__ float b1s[128], b2s[128];

  int tid = threadIdx.x, lane = tid & 63, wid = tid >> 6;

  { const uint4* s = (const uint4*)(wfrag_g + OFF_E1); uint4* d = (uint4*)wE1;
    for (int i = tid; i < 512; i += 384) d[i] = s[i]; }
  { const uint4* s = (const uint4*)(wfrag_g + OFF_E2); uint4* d = (uint4*)wE2;
    for (int i = tid; i < 2048; i += 384) d[i] = s[i]; }
  if (tid < 128) { b1s[tid] = e_b1[tid]; b2s[tid] = e_b2[tid]; }

  int c = lane >> 4, rr = lane & 15;
  int r  = blockIdx.x*96 + wid*16 + rr;     // global row; stripes are 16-aligned so r%NB is uniform-safe
  int rs = r & (NB - 1);                    // self part uses r % B
  uint rq = (uint)r / 6u;                   // neighbor part uses r / K, r % K
  uint rm = (uint)r - rq*6u;

  float xv[8] = {0.f,0.f,0.f,0.f,0.f,0.f,0.f,0.f};
  if (c == 0) {
    #pragma unroll
    for (int j = 0; j < 8; ++j) xv[j] = self_obs[rs*18 + j];
  } else if (c == 1) {
    #pragma unroll
    for (int j = 0; j < 8; ++j) xv[j] = self_obs[rs*18 + 8 + j];
  } else if (c == 2) {
    xv[0] = self_obs[rs*18 + 16];
    xv[1] = self_obs[rs*18 + 17];
    const float* nb = obs + (size_t)rq*54 + 18 + rm*6;
    #pragma unroll
    for (int j = 0; j < 6; ++j) xv[2+j] = nb[j];
  } // c==3: zero pad (weights also zero-padded)
  f16x8 xfrag;
  #pragma unroll
  for (int j = 0; j < 8; ++j) xfrag[j] = (f16)xv[j];

  __syncthreads();

  f32x4 acc[8];
  #pragma unroll
  for (int nt = 0; nt < 8; ++nt) acc[nt] = (f32x4){0.f,0.f,0.f,0.f};
  mfma_layer(acc, &xfrag, wE1, lane, 1);
  write_h_tile(tbuf, acc, b1s, wid, lane);
  LDS_FENCE();
  f16x8 hfrag[4];
  read_h_frags(tbuf, hfrag, wid, lane);

  f32x4 acc2[8];
  #pragma unroll
  for (int nt = 0; nt < 8; ++nt) acc2[nt] = (f32x4){0.f,0.f,0.f,0.f};
  mfma_layer(acc2, hfrag, wE2, lane, 4);
  write_h_tile(tbuf, acc2, b2s, wid, lane);  // emb tile
  __syncthreads();

  // emb -> global (coalesced 16B chunks)
  size_t gbase = (size_t)blockIdx.x * (96*128);
  #pragma unroll
  for (int it = 0; it < 4; ++it) {
    int idx = it*384 + tid;                  // 0..1535 chunk index
    int row = idx >> 4, ch = idx & 15;
    int byte = (row*256 + ch*16) ^ ((row & 7) << 4);
    *(uint4*)(emb_out + gbase + row*128 + ch*8) = *(const uint4*)(tbuf + byte);
  }
  // emb_mean -> global
  int mb0 = blockIdx.x * 16;
  for (int i = tid; i < 2048; i += 384) {
    int b = i >> 7, col = i & 127;
    float s = 0.f;
    #pragma unroll
    for (int k2 = 0; k2 < 6; ++k2) {
      int brow = b*6 + k2;
      int byte = (brow*256 + col*2) ^ ((brow & 7) << 4);
      s += (float)*(const f16*)(tbuf + byte);
    }
    mean_out[(size_t)(mb0 + b)*128 + col] = (f16)(s * (1.0f/6.0f));
  }
}

// ---------------- kernel B: attention MLP + softmax + value MLP + weighted sum ----------------
__global__ void __launch_bounds__(384, 2) att_kernel(
  const f16* __restrict__ wfrag_g, const f16* __restrict__ emb, const f16* __restrict__ meanb,
  const float* __restrict__ a_b1, const float* __restrict__ a_b2,
  const float* __restrict__ a_w3, const float* __restrict__ a_b3,
  const float* __restrict__ v_b1, const float* __restrict__ v_b2,
  float* __restrict__ out)
{
  __shared__ __align__(16) f16 W[16384];       // 32KB staging buffer, reused per layer
  __shared__ __align__(16) char tbuf[24576];
  __shared__ float partial[96][17];            // +1 pad: kills 32-way bank conflict in reduce
  __shared__ float attv[96];
  __shared__ float aw3[128], ab1[128], ab2[128], vb1[128], vb2[128];

  int tid = threadIdx.x, lane = tid & 63, wid = tid >> 6;

  if (tid < 128) { aw3[tid]=a_w3[tid]; ab1[tid]=a_b1[tid]; ab2[tid]=a_b2[tid];
                   vb1[tid]=v_b1[tid]; vb2[tid]=v_b2[tid]; }
  auto stage_w = [&](int off_f16) {
    const uint4* s = (const uint4*)(wfrag_g + off_f16);
    uint4* d = (uint4*)W;
    for (int i2 = tid; i2 < 2048; i2 += 384) d[i2] = s[i2];
  };
  stage_w(OFF_A1);                              // a_w1 k=0..127 (emb part)

  int c = lane >> 4, rr = lane & 15;
  int row  = blockIdx.x*96 + wid*16 + rr;
  int rowm = row & (NB - 1);                    // emb_mean uses r % B
  f16x8 efrag[4], mfrag[4];
  #pragma unroll
  for (int kc = 0; kc < 4; ++kc) {
    efrag[kc] = *(const f16x8*)(emb   + (size_t)row *128 + kc*32 + c*8);
    mfrag[kc] = *(const f16x8*)(meanb + (size_t)rowm*128 + kc*32 + c*8);
  }

  f32x4 acc[8];
  #pragma unroll
  for (int nt = 0; nt < 8; ++nt) acc[nt] = (f32x4){0.f,0.f,0.f,0.f};

  __syncthreads();
  mfma_layer(acc, efrag, W, lane, 4);           // att_in[0:128] @ a_w1[0:128]
  __syncthreads();
  stage_w(OFF_A1 + 16384);                      // a_w1 k=128..255 (mean part)
  __syncthreads();
  mfma_layer(acc, mfrag, W, lane, 4);

  write_h_tile(tbuf, acc, ab1, wid, lane);      // att_h1
  LDS_FENCE();
  f16x8 hfrag[4];
  read_h_frags(tbuf, hfrag, wid, lane);

  __syncthreads();
  stage_w(OFF_A2);
  __syncthreads();
  f32x4 acc2[8];
  #pragma unroll
  for (int nt = 0; nt < 8; ++nt) acc2[nt] = (f32x4){0.f,0.f,0.f,0.f};
  mfma_layer(acc2, hfrag, W, lane, 4);

  // a_w3 dot product: per-lane partial over its 8 columns, LDS-reduce over 16 lanes
  int col0 = rr, q = c;
  float part[4] = {0.f,0.f,0.f,0.f};
  #pragma unroll
  for (int nt = 0; nt < 8; ++nt) {
    int col = nt*16 + col0;
    float w3 = aw3[col], bb = ab2[col];
    #pragma unroll
    for (int rg = 0; rg < 4; ++rg) part[rg] += tanh_fast(acc2[nt][rg] + bb) * w3;
  }
  #pragma unroll
  for (int rg = 0; rg < 4; ++rg) partial[wid*16 + q*4 + rg][col0] = part[rg];
  __syncthreads();
  if (tid < 96) {
    float s = a_b3[0];
    #pragma unroll
    for (int cc = 0; cc < 16; ++cc) s += partial[tid][cc];
    attv[tid] = s;                              // logit for block-row tid
  }
  __syncthreads();
  if (tid < 16) {                               // softmax over each batch's 6 rows
    float l[6]; float m = -1e30f;
    #pragma unroll
    for (int k2 = 0; k2 < 6; ++k2) { l[k2] = attv[tid*6 + k2]; m = fmaxf(m, l[k2]); }
    float ss = 0.f;
    #pragma unroll
    for (int k2 = 0; k2 < 6; ++k2) { l[k2] = __expf(l[k2] - m); ss += l[k2]; }
    float inv = __builtin_amdgcn_rcpf(ss);
    #pragma unroll
    for (int k2 = 0; k2 < 6; ++k2) attv[tid*6 + k2] = l[k2] * inv;
  }

  // ---- value MLP (recomputed from emb fragments kept in registers) ----
  __syncthreads();
  stage_w(OFF_V1);
  __syncthreads();
  f32x4 acc3[8];
  #pragma unroll
  for (int nt = 0; nt < 8; ++nt) acc3[nt] = (f32x4){0.f,0.f,0.f,0.f};
  mfma_layer(acc3, efrag, W, lane, 4);
  write_h_tile(tbuf, acc3, vb1, wid, lane);
  LDS_FENCE();
  read_h_frags(tbuf, hfrag, wid, lane);

  __syncthreads();
  stage_w(OFF_V2);
  __syncthreads();
  f32x4 acc4[8];
  #pragma unroll
  for (int nt = 0; nt < 8; ++nt) acc4[nt] = (f32x4){0.f,0.f,0.f,0.f};
  mfma_layer(acc4, hfrag, W, lane, 4);

  // val = tanh(acc4+vb2) * att[row]  -> swizzled f16 tile
  #pragma unroll
  for (int nt = 0; nt < 8; ++nt) {
    int col = nt*16 + col0;
    float bb = vb2[col];
    #pragma unroll
    for (int rg = 0; rg < 4; ++rg) {
      int brow = wid*16 + q*4 + rg;
      float v = tanh_fast(acc4[nt][rg] + bb) * attv[brow];
      int byte = (brow*256 + col*2) ^ ((brow & 7) << 4);
      *(f16*)(tbuf + byte) = (f16)v;
    }
  }
  __syncthreads();

  // out[b] = sum_k weighted val rows
  int b0 = blockIdx.x * 16;
  for (int i = tid; i < 2048; i += 384) {
    int b = i >> 7, col = i & 127;
    float s = 0.f;
    #pragma unroll
    for (int k2 = 0; k2 < 6; ++k2) {
      int brow = b*6 + k2;
      int byte = (brow*256 + col*2) ^ ((brow & 7) << 4);
      s += (float)*(const f16*)(tbuf + byte);
    }
    out[(size_t)(b0 + b)*128 + col] = s;
  }
}

// ---------------- host launcher ----------------
extern "C" void kernel_launch(void* const* d_in, const int* in_sizes, int n_in,
                              void* d_out, int out_size, void* d_ws, size_t ws_size,
                              hipStream_t stream)
{
  const float* self_obs = (const float*)d_in[0];
  const float* obs  = (const float*)d_in[1];
  const float* e_w1 = (const float*)d_in[2];
  const float* e_b1 = (const float*)d_in[3];
  const float* e_w2 = (const float*)d_in[4];
  const float* e_b2 = (const float*)d_in[5];
  const float* v_w1 = (const float*)d_in[6];
  const float* v_b1 = (const float*)d_in[7];
  const float* v_w2 = (const float*)d_in[8];
  const float* v_b2 = (const float*)d_in[9];
  const float* a_w1 = (const float*)d_in[10];
  const float* a_b1 = (const float*)d_in[11];
  const float* a_w2 = (const float*)d_in[12];
  const float* a_b2 = (const float*)d_in[13];
  const float* a_w3 = (const float*)d_in[14];
  const float* a_b3 = (const float*)d_in[15];

  f16*   wfrag = (f16*)d_ws;
  f16*   emb   = (f16*)((char*)d_ws + EMB_BYTE_OFF);
  f16*   meanb = (f16*)((char*)d_ws + MEAN_BYTE_OFF);
  float* out   = (float*)d_out;

  prep_weights<<<400, 256, 0, stream>>>(e_w1, e_w2, v_w1, v_w2, a_w1, a_w2, wfrag);
  enc_kernel<<<4096, 384, 0, stream>>>(self_obs, obs, e_b1, e_b2, wfrag, emb, meanb);
  att_kernel<<<4096, 384, 0, stream>>>(wfrag, emb, meanb, a_b1, a_b2, a_w3, a_b3,
                                       v_b1, v_b2, out);
}

// Round 4
// 408.926 us; speedup vs baseline: 1.0983x; 1.0983x over previous
//
#include <hip/hip_runtime.h>

typedef _Float16 f16;
typedef f16   f16x8 __attribute__((ext_vector_type(8)));
typedef float f32x4 __attribute__((ext_vector_type(4)));
typedef unsigned int uint;

#define NB     65536
#define NROWS  (NB*6)

// ---- weight-fragment array in d_ws (f16 element offsets) ----
// frag linear index: ((kc*8 + nt)*64 + lane)*8 + j ; k = kc*32 + (lane>>4)*8 + j ; n = nt*16 + (lane&15)
#define OFF_E1 0        // e_w1 24x128 pad->32x128 : 4096 f16
#define OFF_E2 4096     // e_w2 128x128 : 16384
#define OFF_V1 20480
#define OFF_V2 36864
#define OFF_A1 53248    // a_w1 256x128 : 32768 (kc0-3 emb half, kc4-7 mean half)
#define OFF_A2 86016
#define WFRAG_TOTAL 102400

#define EMB_BYTE_OFF   204800ull                       // NROWS x 128 f16
#define MEAN_BYTE_OFF  (204800ull + 100663296ull)      // NB x 128 f16

#define LDS_FENCE() asm volatile("s_waitcnt lgkmcnt(0)" ::: "memory")
#define WAIT_VM(N)  asm volatile("s_waitcnt vmcnt(" #N ")" ::: "memory")
#define BAR()       { __builtin_amdgcn_s_barrier(); __builtin_amdgcn_sched_barrier(0); }

__device__ __forceinline__ float tanh_fast(float x) {
  float e = __expf(2.0f * x);
  return 1.0f - 2.0f * __builtin_amdgcn_rcpf(e + 1.0f);
}

// ---------------- prep: f32 weights -> f16 fragment order (R2 verbatim) ----------------
__global__ void prep_weights(const float* __restrict__ e1, const float* __restrict__ e2,
                             const float* __restrict__ v1, const float* __restrict__ v2,
                             const float* __restrict__ a1, const float* __restrict__ a2,
                             f16* __restrict__ dst)
{
  int i = blockIdx.x * 256 + threadIdx.x;
  if (i >= WFRAG_TOTAL) return;
  const float* src; int base, Ksrc;
  if      (i < OFF_E2) { src = e1; base = OFF_E1; Ksrc = 24;  }
  else if (i < OFF_V1) { src = e2; base = OFF_E2; Ksrc = 128; }
  else if (i < OFF_V2) { src = v1; base = OFF_V1; Ksrc = 128; }
  else if (i < OFF_A1) { src = v2; base = OFF_V2; Ksrc = 128; }
  else if (i < OFF_A2) { src = a1; base = OFF_A1; Ksrc = 256; }
  else                 { src = a2; base = OFF_A2; Ksrc = 128; }
  int li   = i - base;
  int j    = li & 7;
  int lane = (li >> 3) & 63;
  int nt   = (li >> 9) & 7;
  int kc   = li >> 12;
  int k = kc*32 + (lane >> 4)*8 + j;
  int n = nt*16 + (lane & 15);
  float v = (k < Ksrc) ? src[k*128 + n] : 0.0f;
  dst[i] = (f16)v;
}

// ---------------- shared device helpers ----------------
__device__ __forceinline__ void mfma_layer(f32x4* acc, const f16x8* afrag, const f16* W,
                                           int lane, int nkc)
{
  #pragma unroll
  for (int kc = 0; kc < nkc; ++kc) {
    #pragma unroll
    for (int nt = 0; nt < 8; ++nt) {
      f16x8 wf = *(const f16x8*)(W + (((kc*8 + nt)*64) + lane)*8);
      acc[nt] = __builtin_amdgcn_mfma_f32_16x16x32_f16(afrag[kc], wf, acc[nt], 0, 0, 0);
    }
  }
}

// 2-kc half-layer MFMA from a 16KB LDS weight buffer
__device__ __forceinline__ void mfma2(f32x4* acc, f16x8 a0, f16x8 a1, const f16* Wb, int lane)
{
  #pragma unroll
  for (int nt = 0; nt < 8; ++nt) {
    f16x8 w = *(const f16x8*)(Wb + (nt*64 + lane)*8);
    acc[nt] = __builtin_amdgcn_mfma_f32_16x16x32_f16(a0, w, acc[nt], 0, 0, 0);
  }
  #pragma unroll
  for (int nt = 0; nt < 8; ++nt) {
    f16x8 w = *(const f16x8*)(Wb + ((8+nt)*64 + lane)*8);
    acc[nt] = __builtin_amdgcn_mfma_f32_16x16x32_f16(a1, w, acc[nt], 0, 0, 0);
  }
}

// tanh(acc+bias) -> swizzled f16 tile rows [wid*16, wid*16+16)
__device__ __forceinline__ void write_h_tile(char* tbuf, const f32x4* acc, const float* bias,
                                             int wid, int lane)
{
  int col0 = lane & 15, q = lane >> 4;
  #pragma unroll
  for (int nt = 0; nt < 8; ++nt) {
    int col = nt*16 + col0;
    float b = bias[col];
    #pragma unroll
    for (int rg = 0; rg < 4; ++rg) {
      int row = wid*16 + q*4 + rg;          // C/D: col=lane&15, row=(lane>>4)*4+rg
      float h = tanh_fast(acc[nt][rg] + b);
      int byte = (row*256 + col*2) ^ ((row & 7) << 4);
      *(f16*)(tbuf + byte) = (f16)h;
    }
  }
}

__device__ __forceinline__ void read_h_frags(const char* tbuf, f16x8* frag, int wid, int lane)
{
  int c = lane >> 4, rr = lane & 15;
  int row = wid*16 + rr;                    // A: row=lane&15, k=(lane>>4)*8+j
  #pragma unroll
  for (int kc = 0; kc < 4; ++kc) {
    int byte = (row*256 + kc*64 + c*16) ^ ((row & 7) << 4);
    frag[kc] = *(const f16x8*)(tbuf + byte);
  }
}

__device__ __forceinline__ void gload_lds16(const f16* g, f16* l) {
  __builtin_amdgcn_global_load_lds(
    (const __attribute__((address_space(1))) unsigned int*)g,
    (__attribute__((address_space(3))) unsigned int*)l, 16, 0, 0);
}
// 16KB stage with 384 threads: 3 wave-ops per wave exactly (wrap duplicates are benign)
__device__ __forceinline__ void stage16(const f16* g, f16* l, int tid) {
  #pragma unroll
  for (int it = 0; it < 3; ++it) {
    int idx = (tid + it*384) & 1023;
    gload_lds16(g + idx*8, l + idx*8);
  }
}

// ---------------- kernel A: encoder MLP (R2 verbatim) ----------------
__global__ void __launch_bounds__(384, 2) enc_kernel(
  const float* __restrict__ self_obs, const float* __restrict__ obs,
  const float* __restrict__ e_b1, const float* __restrict__ e_b2,
  const f16* __restrict__ wfrag_g, f16* __restrict__ emb_out, f16* __restrict__ mean_out)
{
  __shared__ __align__(16) f16 wE1[4096];
  __shared__ __align__(16) f16 wE2[16384];
  __shared__ __align__(16) char tbuf[24576];   // 96 x 128 f16, XOR-swizzled
  __shared__ float b1s[128], b2s[128];

  int tid = threadIdx.x, lane = tid & 63, wid = tid >> 6;

  { const uint4* s = (const uint4*)(wfrag_g + OFF_E1); uint4* d = (uint4*)wE1;
    for (int i = tid; i < 512; i += 384) d[i] = s[i]; }
  { const uint4* s = (const uint4*)(wfrag_g + OFF_E2); uint4* d = (uint4*)wE2;
    for (int i = tid; i < 2048; i += 384) d[i] = s[i]; }
  if (tid < 128) { b1s[tid] = e_b1[tid]; b2s[tid] = e_b2[tid]; }

  int c = lane >> 4, rr = lane & 15;
  int r  = blockIdx.x*96 + wid*16 + rr;
  int rs = r & (NB - 1);                    // self part uses r % B
  uint rq = (uint)r / 6u;                   // neighbor part uses r / K, r % K
  uint rm = (uint)r - rq*6u;

  float xv[8] = {0.f,0.f,0.f,0.f,0.f,0.f,0.f,0.f};
  if (c == 0) {
    #pragma unroll
    for (int j = 0; j < 8; ++j) xv[j] = self_obs[rs*18 + j];
  } else if (c == 1) {
    #pragma unroll
    for (int j = 0; j < 8; ++j) xv[j] = self_obs[rs*18 + 8 + j];
  } else if (c == 2) {
    xv[0] = self_obs[rs*18 + 16];
    xv[1] = self_obs[rs*18 + 17];
    const float* nb = obs + (size_t)rq*54 + 18 + rm*6;
    #pragma unroll
    for (int j = 0; j < 6; ++j) xv[2+j] = nb[j];
  } // c==3: zero pad
  f16x8 xfrag;
  #pragma unroll
  for (int j = 0; j < 8; ++j) xfrag[j] = (f16)xv[j];

  __syncthreads();

  f32x4 acc[8];
  #pragma unroll
  for (int nt = 0; nt < 8; ++nt) acc[nt] = (f32x4){0.f,0.f,0.f,0.f};
  mfma_layer(acc, &xfrag, wE1, lane, 1);
  write_h_tile(tbuf, acc, b1s, wid, lane);
  LDS_FENCE();
  f16x8 hfrag[4];
  read_h_frags(tbuf, hfrag, wid, lane);

  f32x4 acc2[8];
  #pragma unroll
  for (int nt = 0; nt < 8; ++nt) acc2[nt] = (f32x4){0.f,0.f,0.f,0.f};
  mfma_layer(acc2, hfrag, wE2, lane, 4);
  write_h_tile(tbuf, acc2, b2s, wid, lane);  // emb tile
  __syncthreads();

  // emb -> global (coalesced 16B chunks)
  size_t gbase = (size_t)blockIdx.x * (96*128);
  #pragma unroll
  for (int it = 0; it < 4; ++it) {
    int idx = it*384 + tid;
    int row = idx >> 4, ch = idx & 15;
    int byte = (row*256 + ch*16) ^ ((row & 7) << 4);
    *(uint4*)(emb_out + gbase + row*128 + ch*8) = *(const uint4*)(tbuf + byte);
  }
  // emb_mean -> global
  int mb0 = blockIdx.x * 16;
  for (int i = tid; i < 2048; i += 384) {
    int b = i >> 7, col = i & 127;
    float s = 0.f;
    #pragma unroll
    for (int k2 = 0; k2 < 6; ++k2) {
      int brow = b*6 + k2;
      int byte = (brow*256 + col*2) ^ ((brow & 7) << 4);
      s += (float)*(const f16*)(tbuf + byte);
    }
    mean_out[(size_t)(mb0 + b)*128 + col] = (f16)(s * (1.0f/6.0f));
  }
}

// ---------------- kernel B: R2 logic + counted-vmcnt double-buffered weight pipeline ----------------
__global__ void __launch_bounds__(384, 2) att_kernel(
  const f16* __restrict__ wfrag_g, const f16* __restrict__ emb, const f16* __restrict__ meanb,
  const float* __restrict__ a_b1, const float* __restrict__ a_b2,
  const float* __restrict__ a_w3, const float* __restrict__ a_b3,
  const float* __restrict__ v_b1, const float* __restrict__ v_b2,
  float* __restrict__ out)
{
  __shared__ __align__(16) f16 W[2][8192];       // 2 x 16KB stage buffers
  __shared__ __align__(16) char tbuf[24576];
  __shared__ float partial[96][17];
  __shared__ float attv[96];
  __shared__ float aw3[128], ab1[128], ab2[128], vb1[128], vb2[128];

  int tid = threadIdx.x, lane = tid & 63, wid = tid >> 6;

  if (tid < 128) { aw3[tid]=a_w3[tid]; ab1[tid]=a_b1[tid]; ab2[tid]=a_b2[tid];
                   vb1[tid]=v_b1[tid]; vb2[tid]=v_b2[tid]; }

  int c = lane >> 4, rr = lane & 15;
  int row  = blockIdx.x*96 + wid*16 + rr;
  int rowm = row & (NB - 1);                    // emb_mean uses r % B
  f16x8 ef[4], mf[4];
  #pragma unroll
  for (int kc = 0; kc < 4; ++kc) {
    ef[kc] = *(const f16x8*)(emb   + (size_t)row *128 + kc*32 + c*8);
    mf[kc] = *(const f16x8*)(meanb + (size_t)rowm*128 + kc*32 + c*8);
  }
  __builtin_amdgcn_sched_barrier(0);
  stage16(wfrag_g + OFF_A1,        &W[0][0], tid);     // S0: A1 kc01
  stage16(wfrag_g + OFF_A1 + 8192, &W[1][0], tid);     // S1: A1 kc23
  __builtin_amdgcn_sched_barrier(0);

  f32x4 acc[8];
  #pragma unroll
  for (int nt = 0; nt < 8; ++nt) acc[nt] = (f32x4){0.f,0.f,0.f,0.f};

  LDS_FENCE();                                  // bias LDS writes visible before raw barrier
  // P0..P3: att layer 1 (K=256)
  WAIT_VM(3); BAR();
  mfma2(acc, ef[0], ef[1], &W[0][0], lane);
  BAR(); stage16(wfrag_g + OFF_A1 + 16384, &W[0][0], tid);   // S2: A1 kc45 (mean half)
  WAIT_VM(3); BAR();
  mfma2(acc, ef[2], ef[3], &W[1][0], lane);
  BAR(); stage16(wfrag_g + OFF_A1 + 24576, &W[1][0], tid);   // S3: A1 kc67
  WAIT_VM(3); BAR();
  mfma2(acc, mf[0], mf[1], &W[0][0], lane);
  BAR(); stage16(wfrag_g + OFF_A2,        &W[0][0], tid);    // S4: A2 kc01
  WAIT_VM(3); BAR();
  mfma2(acc, mf[2], mf[3], &W[1][0], lane);
  BAR(); stage16(wfrag_g + OFF_A2 + 8192, &W[1][0], tid);    // S5: A2 kc23

  // h1 epilogue (wave-private)
  write_h_tile(tbuf, acc, ab1, wid, lane);
  LDS_FENCE();
  f16x8 hf[4];
  read_h_frags(tbuf, hf, wid, lane);

  f32x4 acc2[8];
  #pragma unroll
  for (int nt = 0; nt < 8; ++nt) acc2[nt] = (f32x4){0.f,0.f,0.f,0.f};
  // P4..P5: att layer 2
  WAIT_VM(3); BAR();
  mfma2(acc2, hf[0], hf[1], &W[0][0], lane);
  BAR(); stage16(wfrag_g + OFF_V1,        &W[0][0], tid);    // S6
  WAIT_VM(3); BAR();
  mfma2(acc2, hf[2], hf[3], &W[1][0], lane);
  BAR(); stage16(wfrag_g + OFF_V1 + 8192, &W[1][0], tid);    // S7

  // logits + softmax (R2 verbatim; __syncthreads drains are prologue-safe)
  int col0 = rr, q = c;
  float part[4] = {0.f,0.f,0.f,0.f};
  #pragma unroll
  for (int nt = 0; nt < 8; ++nt) {
    int col = nt*16 + col0;
    float w3 = aw3[col], bb = ab2[col];
    #pragma unroll
    for (int rg = 0; rg < 4; ++rg) part[rg] += tanh_fast(acc2[nt][rg] + bb) * w3;
  }
  #pragma unroll
  for (int rg = 0; rg < 4; ++rg) partial[wid*16 + q*4 + rg][col0] = part[rg];
  __syncthreads();
  if (tid < 96) {
    float s = a_b3[0];
    #pragma unroll
    for (int cc = 0; cc < 16; ++cc) s += partial[tid][cc];
    attv[tid] = s;
  }
  __syncthreads();
  if (tid < 16) {
    float l[6]; float m = -1e30f;
    #pragma unroll
    for (int k2 = 0; k2 < 6; ++k2) { l[k2] = attv[tid*6 + k2]; m = fmaxf(m, l[k2]); }
    float ss = 0.f;
    #pragma unroll
    for (int k2 = 0; k2 < 6; ++k2) { l[k2] = __expf(l[k2] - m); ss += l[k2]; }
    float inv = __builtin_amdgcn_rcpf(ss);
    #pragma unroll
    for (int k2 = 0; k2 < 6; ++k2) attv[tid*6 + k2] = l[k2] * inv;
  }
  __syncthreads();

  // P6..P7: value layer 1
  f32x4 acc3[8];
  #pragma unroll
  for (int nt = 0; nt < 8; ++nt) acc3[nt] = (f32x4){0.f,0.f,0.f,0.f};
  WAIT_VM(3); BAR();
  mfma2(acc3, ef[0], ef[1], &W[0][0], lane);
  BAR(); stage16(wfrag_g + OFF_V2,        &W[0][0], tid);    // S8
  WAIT_VM(3); BAR();
  mfma2(acc3, ef[2], ef[3], &W[1][0], lane);
  BAR(); stage16(wfrag_g + OFF_V2 + 8192, &W[1][0], tid);    // S9

  write_h_tile(tbuf, acc3, vb1, wid, lane);
  LDS_FENCE();
  read_h_frags(tbuf, hf, wid, lane);

  // P8..P9: value layer 2
  f32x4 acc4[8];
  #pragma unroll
  for (int nt = 0; nt < 8; ++nt) acc4[nt] = (f32x4){0.f,0.f,0.f,0.f};
  WAIT_VM(3); BAR();
  mfma2(acc4, hf[0], hf[1], &W[0][0], lane);
  WAIT_VM(0); BAR();
  mfma2(acc4, hf[2], hf[3], &W[1][0], lane);

  // val = tanh(acc4+vb2) * att[row] -> swizzled f16 tile (R2 verbatim)
  #pragma unroll
  for (int nt = 0; nt < 8; ++nt) {
    int col = nt*16 + col0;
    float bb = vb2[col];
    #pragma unroll
    for (int rg = 0; rg < 4; ++rg) {
      int brow = wid*16 + q*4 + rg;
      float v = tanh_fast(acc4[nt][rg] + bb) * attv[brow];
      int byte = (brow*256 + col*2) ^ ((brow & 7) << 4);
      *(f16*)(tbuf + byte) = (f16)v;
    }
  }
  __syncthreads();

  // out[b] = sum_k weighted val rows (R2 verbatim)
  int b0 = blockIdx.x * 16;
  for (int i = tid; i < 2048; i += 384) {
    int b = i >> 7, col = i & 127;
    float s = 0.f;
    #pragma unroll
    for (int k2 = 0; k2 < 6; ++k2) {
      int brow = b*6 + k2;
      int byte = (brow*256 + col*2) ^ ((brow & 7) << 4);
      s += (float)*(const f16*)(tbuf + byte);
    }
    out[(size_t)(b0 + b)*128 + col] = s;
  }
}

// ---------------- host launcher ----------------
extern "C" void kernel_launch(void* const* d_in, const int* in_sizes, int n_in,
                              void* d_out, int out_size, void* d_ws, size_t ws_size,
                              hipStream_t stream)
{
  const float* self_obs = (const float*)d_in[0];
  const float* obs  = (const float*)d_in[1];
  const float* e_w1 = (const float*)d_in[2];
  const float* e_b1 = (const float*)d_in[3];
  const float* e_w2 = (const float*)d_in[4];
  const float* e_b2 = (const float*)d_in[5];
  const float* v_w1 = (const float*)d_in[6];
  const float* v_b1 = (const float*)d_in[7];
  const float* v_w2 = (const float*)d_in[8];
  const float* v_b2 = (const float*)d_in[9];
  const float* a_w1 = (const float*)d_in[10];
  const float* a_b1 = (const float*)d_in[11];
  const float* a_w2 = (const float*)d_in[12];
  const float* a_b2 = (const float*)d_in[13];
  const float* a_w3 = (const float*)d_in[14];
  const float* a_b3 = (const float*)d_in[15];

  f16*   wfrag = (f16*)d_ws;
  f16*   emb   = (f16*)((char*)d_ws + EMB_BYTE_OFF);
  f16*   meanb = (f16*)((char*)d_ws + MEAN_BYTE_OFF);
  float* out   = (float*)d_out;

  prep_weights<<<400, 256, 0, stream>>>(e_w1, e_w2, v_w1, v_w2, a_w1, a_w2, wfrag);
  enc_kernel<<<4096, 384, 0, stream>>>(self_obs, obs, e_b1, e_b2, wfrag, emb, meanb);
  att_kernel<<<4096, 384, 0, stream>>>(wfrag, emb, meanb, a_b1, a_b2, a_w3, a_b3,
                                       v_b1, v_b2, out);
}

// Round 5
// 365.256 us; speedup vs baseline: 1.2296x; 1.1196x over previous
//
#include <hip/hip_runtime.h>

typedef _Float16 f16;
typedef f16   f16x8 __attribute__((ext_vector_type(8)));
typedef float f32x4 __attribute__((ext_vector_type(4)));
typedef unsigned int uint;

#define NB     65536
#define NROWS  (NB*6)
#define NTILES 4096      // 96-row tiles
#define TPB    16        // tiles per persistent block (4096 / 256)

// ---- weight-fragment array in d_ws (f16 element offsets) ----
// frag linear index: ((kc*8 + nt)*64 + lane)*8 + j ; k = kc*32 + (lane>>4)*8 + j ; n = nt*16 + (lane&15)
#define OFF_E1 0        // e_w1 24x128 pad->32x128 : 4096 f16
#define OFF_E2 4096     // e_w2 128x128 : 16384
#define OFF_V1 20480
#define OFF_V2 36864
#define OFF_A1 53248    // a_w1 256x128 : 32768 (kc0-3 emb half, kc4-7 mean half)
#define OFF_A2 86016
#define WFRAG_TOTAL 102400

#define EMB_BYTE_OFF   204800ull                       // NROWS x 128 f16
#define MEANH_BYTE_OFF (204800ull + 100663296ull)      // NB x 128 f16 (meanh1 = mean@A1m + a_b1)

#define LDS_FENCE() asm volatile("s_waitcnt lgkmcnt(0)" ::: "memory")
#define WAIT_VM0()  asm volatile("s_waitcnt vmcnt(0)" ::: "memory")
#define BAR()       { __builtin_amdgcn_s_barrier(); __builtin_amdgcn_sched_barrier(0); }

__device__ __forceinline__ float tanh_fast(float x) {
  float e = __expf(2.0f * x);
  return 1.0f - 2.0f * __builtin_amdgcn_rcpf(e + 1.0f);
}

// ---------------- prep: f32 weights -> f16 fragment order (verbatim) ----------------
__global__ void prep_weights(const float* __restrict__ e1, const float* __restrict__ e2,
                             const float* __restrict__ v1, const float* __restrict__ v2,
                             const float* __restrict__ a1, const float* __restrict__ a2,
                             f16* __restrict__ dst)
{
  int i = blockIdx.x * 256 + threadIdx.x;
  if (i >= WFRAG_TOTAL) return;
  const float* src; int base, Ksrc;
  if      (i < OFF_E2) { src = e1; base = OFF_E1; Ksrc = 24;  }
  else if (i < OFF_V1) { src = e2; base = OFF_E2; Ksrc = 128; }
  else if (i < OFF_V2) { src = v1; base = OFF_V1; Ksrc = 128; }
  else if (i < OFF_A1) { src = v2; base = OFF_V2; Ksrc = 128; }
  else if (i < OFF_A2) { src = a1; base = OFF_A1; Ksrc = 256; }
  else                 { src = a2; base = OFF_A2; Ksrc = 128; }
  int li   = i - base;
  int j    = li & 7;
  int lane = (li >> 3) & 63;
  int nt   = (li >> 9) & 7;
  int kc   = li >> 12;
  int k = kc*32 + (lane >> 4)*8 + j;
  int n = nt*16 + (lane & 15);
  float v = (k < Ksrc) ? src[k*128 + n] : 0.0f;
  dst[i] = (f16)v;
}

// ---------------- shared helpers ----------------
// 2-kc half-layer MFMA from an LDS weight buffer (verbatim R4)
__device__ __forceinline__ void mfma2(f32x4* acc, f16x8 a0, f16x8 a1, const f16* Wb, int lane)
{
  #pragma unroll
  for (int nt = 0; nt < 8; ++nt) {
    f16x8 w = *(const f16x8*)(Wb + (nt*64 + lane)*8);
    acc[nt] = __builtin_amdgcn_mfma_f32_16x16x32_f16(a0, w, acc[nt], 0, 0, 0);
  }
  #pragma unroll
  for (int nt = 0; nt < 8; ++nt) {
    f16x8 w = *(const f16x8*)(Wb + ((8+nt)*64 + lane)*8);
    acc[nt] = __builtin_amdgcn_mfma_f32_16x16x32_f16(a1, w, acc[nt], 0, 0, 0);
  }
}

// tanh(acc + bias8[nt]) -> swizzled f16 tile rows [wid*16, wid*16+16)  (reg-bias variant of R2 helper)
__device__ __forceinline__ void epi_tanh_store(char* tb, const f32x4* acc, const float* bias8,
                                               int wid, int lane)
{
  int col0 = lane & 15, q = lane >> 4;
  #pragma unroll
  for (int nt = 0; nt < 8; ++nt) {
    #pragma unroll
    for (int rg = 0; rg < 4; ++rg) {
      int row = wid*16 + q*4 + rg;          // C/D: col=lane&15, row=(lane>>4)*4+rg
      float h = tanh_fast(acc[nt][rg] + bias8[nt]);
      int byte = (row*256 + (nt*16 + col0)*2) ^ ((row & 7) << 4);
      *(f16*)(tb + byte) = (f16)h;
    }
  }
}

__device__ __forceinline__ void read_h_frags(const char* tb, f16x8* frag, int wid, int lane)
{
  int c = lane >> 4, rr = lane & 15;
  int row = wid*16 + rr;                    // A: row=lane&15, k=(lane>>4)*8+j
  #pragma unroll
  for (int kc = 0; kc < 4; ++kc) {
    int byte = (row*256 + kc*64 + c*16) ^ ((row & 7) << 4);
    frag[kc] = *(const f16x8*)(tb + byte);
  }
}

__device__ __forceinline__ void gload_lds16(const f16* g, f16* l) {
  __builtin_amdgcn_global_load_lds(
    (const __attribute__((address_space(1))) unsigned int*)g,
    (__attribute__((address_space(3))) unsigned int*)l, 16, 0, 0);
}

// R2-verbatim input gather (one MFMA A-fragment of the 24-wide padded input)
__device__ __forceinline__ f16x8 gather_x(const float* __restrict__ so, const float* __restrict__ obs,
                                          int r, int c)
{
  int rs = r & (NB - 1);
  uint rq = (uint)r / 6u;
  uint rm = (uint)r - rq*6u;
  float xv[8] = {0.f,0.f,0.f,0.f,0.f,0.f,0.f,0.f};
  if (c == 0) {
    #pragma unroll
    for (int j = 0; j < 8; ++j) xv[j] = so[rs*18 + j];
  } else if (c == 1) {
    #pragma unroll
    for (int j = 0; j < 8; ++j) xv[j] = so[rs*18 + 8 + j];
  } else if (c == 2) {
    xv[0] = so[rs*18 + 16];
    xv[1] = so[rs*18 + 17];
    const float* nb = obs + (size_t)rq*54 + 18 + rm*6;
    #pragma unroll
    for (int j = 0; j < 6; ++j) xv[2+j] = nb[j];
  } // c==3: zero pad
  f16x8 f;
  #pragma unroll
  for (int j = 0; j < 8; ++j) f[j] = (f16)xv[j];
  return f;
}

// ---------------- kernel A: persistent encoder + meanh1 precompute ----------------
__global__ void __launch_bounds__(384, 1) enc_kernel(
  const float* __restrict__ self_obs, const float* __restrict__ obs,
  const float* __restrict__ e_b1, const float* __restrict__ e_b2,
  const float* __restrict__ a_b1,
  const f16* __restrict__ wfrag, f16* __restrict__ emb_out, f16* __restrict__ meanh_out)
{
  __shared__ __align__(16) f16 wE1[4096];     //  8 KB resident
  __shared__ __align__(16) f16 wE2[16384];    // 32 KB resident
  __shared__ __align__(16) f16 wA1m[16384];   // 32 KB resident (a_w1 mean half)
  __shared__ __align__(16) char tbuf[24576];  // 96x128 f16 swizzled
  __shared__ __align__(16) char mbuf[4096];   // 16x128 f16 swizzled (means / meanh1)

  int tid = threadIdx.x, lane = tid & 63, wid = tid >> 6;
  int c = lane >> 4, rr = lane & 15;

  // resident weight preload (wave-uniform guards)
  #pragma unroll
  for (int it = 0; it < 2; ++it) { int idx = it*384 + tid; if (idx < 512)  gload_lds16(wfrag + OFF_E1 + idx*8, wE1 + idx*8); }
  #pragma unroll
  for (int it = 0; it < 6; ++it) { int idx = it*384 + tid; if (idx < 2048) gload_lds16(wfrag + OFF_E2 + idx*8, wE2 + idx*8); }
  #pragma unroll
  for (int it = 0; it < 6; ++it) { int idx = it*384 + tid; if (idx < 2048) gload_lds16(wfrag + OFF_A1 + 16384 + idx*8, wA1m + idx*8); }

  float b1r[8], b2r[8], ab1r[8];
  #pragma unroll
  for (int nt = 0; nt < 8; ++nt) {
    int col = nt*16 + rr;
    b1r[nt] = e_b1[col]; b2r[nt] = e_b2[col]; ab1r[nt] = a_b1[col];
  }

  int t0 = blockIdx.x * TPB;
  f16x8 xfrag = gather_x(self_obs, obs, t0*96 + wid*16 + rr, c);
  WAIT_VM0(); BAR();

  for (int i = 0; i < TPB; ++i) {
    int t = t0 + i;
    // layer 1 (K=32)
    f32x4 acc[8];
    #pragma unroll
    for (int nt = 0; nt < 8; ++nt) acc[nt] = (f32x4){0.f,0.f,0.f,0.f};
    #pragma unroll
    for (int nt = 0; nt < 8; ++nt) {
      f16x8 w = *(const f16x8*)(wE1 + (nt*64 + lane)*8);
      acc[nt] = __builtin_amdgcn_mfma_f32_16x16x32_f16(xfrag, w, acc[nt], 0, 0, 0);
    }
    epi_tanh_store(tbuf, acc, b1r, wid, lane);
    LDS_FENCE();
    f16x8 hf[4];
    read_h_frags(tbuf, hf, wid, lane);

    // prefetch next tile's input during layer 2
    f16x8 xnext = gather_x(self_obs, obs,
                           ((i+1 < TPB) ? (t+1) : t0)*96 + wid*16 + rr, c);

    // layer 2 (K=128)
    f32x4 acc2[8];
    #pragma unroll
    for (int nt = 0; nt < 8; ++nt) acc2[nt] = (f32x4){0.f,0.f,0.f,0.f};
    mfma2(acc2, hf[0], hf[1], wE2,        lane);
    mfma2(acc2, hf[2], hf[3], wE2 + 8192, lane);
    epi_tanh_store(tbuf, acc2, b2r, wid, lane);   // emb tile
    LDS_FENCE(); BAR();

    // emb -> global (R2-verbatim)
    size_t gbase = (size_t)t * (96*128);
    #pragma unroll
    for (int it2 = 0; it2 < 4; ++it2) {
      int idx = it2*384 + tid;
      int row = idx >> 4, ch = idx & 15;
      int byte = (row*256 + ch*16) ^ ((row & 7) << 4);
      *(uint4*)(emb_out + gbase + row*128 + ch*8) = *(const uint4*)(tbuf + byte);
    }
    // mean -> mbuf (swizzled)
    for (int i2 = tid; i2 < 2048; i2 += 384) {
      int b = i2 >> 7, col = i2 & 127;
      float s = 0.f;
      #pragma unroll
      for (int k2 = 0; k2 < 6; ++k2) {
        int brow = b*6 + k2;
        int byte = (brow*256 + col*2) ^ ((brow & 7) << 4);
        s += (float)*(const f16*)(tbuf + byte);
      }
      int mb = (b*256 + col*2) ^ ((b & 7) << 4);
      *(f16*)(mbuf + mb) = (f16)(s * (1.0f/6.0f));
    }
    LDS_FENCE(); BAR();

    // mean MFMA: all waves read frags, barrier, redundant compute; wave0 writes meanh1
    f16x8 mfr[4];
    read_h_frags(mbuf, mfr, 0, lane);
    LDS_FENCE(); BAR();
    f32x4 accm[8];
    #pragma unroll
    for (int nt = 0; nt < 8; ++nt) accm[nt] = (f32x4){0.f,0.f,0.f,0.f};
    mfma2(accm, mfr[0], mfr[1], wA1m,        lane);
    mfma2(accm, mfr[2], mfr[3], wA1m + 8192, lane);
    if (wid == 0) {
      #pragma unroll
      for (int nt = 0; nt < 8; ++nt) {
        #pragma unroll
        for (int rg = 0; rg < 4; ++rg) {
          int row = c*4 + rg;
          int byte = (row*256 + (nt*16 + rr)*2) ^ ((row & 7) << 4);
          *(f16*)(mbuf + byte) = (f16)(accm[nt][rg] + ab1r[nt]);   // NO tanh (pre-activation)
        }
      }
      LDS_FENCE();
      // copy out plain row-major (unswizzle chunks)
      #pragma unroll
      for (int it2 = 0; it2 < 4; ++it2) {
        int slot = it2*64 + lane;
        int row = slot >> 4, ch = slot & 15;
        int byte = (row*256 + ch*16) ^ ((row & 7) << 4);
        *(uint4*)(meanh_out + (size_t)(t*16 + row)*128 + ch*8) = *(const uint4*)(mbuf + byte);
      }
      LDS_FENCE();
    }
    xfrag = xnext;
    BAR();
  }
}

// ---------------- kernel B: persistent att+val, weights fully LDS-resident ----------------
__global__ void __launch_bounds__(384, 1) att_kernel(
  const f16* __restrict__ wfrag, const f16* __restrict__ emb, const f16* __restrict__ meanh,
  const float* __restrict__ a_b2, const float* __restrict__ a_w3, const float* __restrict__ a_b3,
  const float* __restrict__ v_b1, const float* __restrict__ v_b2,
  float* __restrict__ out)
{
  __shared__ __align__(16) f16 W[4][16384];   // A1emb, A2, V1, V2 : 128 KB resident
  __shared__ __align__(16) char tbuf[24576];  // meanh1 tile -> h/val transposes (double duty)
  __shared__ float partial[96][17];
  __shared__ float attv[96];

  int tid = threadIdx.x, lane = tid & 63, wid = tid >> 6;
  int c = lane >> 4, rr = lane & 15;

  // resident weight preload
  #pragma unroll
  for (int m = 0; m < 4; ++m) {
    const int offs[4] = {OFF_A1, OFF_A2, OFF_V1, OFF_V2};
    const f16* s = wfrag + offs[m];
    #pragma unroll
    for (int it = 0; it < 6; ++it) {
      int idx = it*384 + tid;
      if (idx < 2048) gload_lds16(s + idx*8, &W[m][0] + idx*8);
    }
  }

  float aw3r[8], ab2r[8], vb1r[8], vb2r[8];
  #pragma unroll
  for (int nt = 0; nt < 8; ++nt) {
    int col = nt*16 + rr;
    aw3r[nt] = a_w3[col]; ab2r[nt] = a_b2[col]; vb1r[nt] = v_b1[col]; vb2r[nt] = v_b2[col];
  }
  float ab3r = a_b3[0];

  int t0 = blockIdx.x * TPB;
  f16x8 ef[4];
  {
    size_t r = (size_t)t0*96 + wid*16 + rr;
    #pragma unroll
    for (int kc = 0; kc < 4; ++kc) ef[kc] = *(const f16x8*)(emb + r*128 + kc*32 + c*8);
  }
  WAIT_VM0(); BAR();

  for (int i = 0; i < TPB; ++i) {
    int t = t0 + i;
    int rowbase = t*96;

    // stage meanh1 tile into tbuf (swizzle via pre-permuted source chunks)
    #pragma unroll
    for (int it = 0; it < 4; ++it) {
      int slot = (wid*4 + it)*64 + lane;
      int row = slot >> 4, ch = slot & 15;
      int gr = (rowbase + row) & (NB - 1);              // mean index = row % B (reference quirk)
      gload_lds16(meanh + (size_t)gr*128 + (ch ^ (row & 7))*8, (f16*)(tbuf + slot*16));
    }

    // att layer 1: emb @ A1emb (meanh1 added at epilogue)
    f32x4 acc[8];
    #pragma unroll
    for (int nt = 0; nt < 8; ++nt) acc[nt] = (f32x4){0.f,0.f,0.f,0.f};
    mfma2(acc, ef[0], ef[1], &W[0][0],    lane);
    mfma2(acc, ef[2], ef[3], &W[0][8192], lane);
    WAIT_VM0(); BAR();                                  // meanh1 stage visible

    // prefetch next tile's emb frags
    f16x8 efn[4];
    {
      int tn = (i+1 < TPB) ? (t+1) : t;
      size_t r = (size_t)tn*96 + wid*16 + rr;
      #pragma unroll
      for (int kc = 0; kc < 4; ++kc) efn[kc] = *(const f16x8*)(emb + r*128 + kc*32 + c*8);
    }

    // L1 epilogue: h1 = tanh(acc + meanh1[row%B][col]); same-lane overwrite into tbuf
    #pragma unroll
    for (int nt = 0; nt < 8; ++nt) {
      #pragma unroll
      for (int rg = 0; rg < 4; ++rg) {
        int row = wid*16 + c*4 + rg;
        int byte = (row*256 + (nt*16 + rr)*2) ^ ((row & 7) << 4);
        float mh = (float)*(const f16*)(tbuf + byte);
        float h = tanh_fast(acc[nt][rg] + mh);
        *(f16*)(tbuf + byte) = (f16)h;
      }
    }
    LDS_FENCE();
    f16x8 hf[4];
    read_h_frags(tbuf, hf, wid, lane);

    // att layer 2
    f32x4 acc2[8];
    #pragma unroll
    for (int nt = 0; nt < 8; ++nt) acc2[nt] = (f32x4){0.f,0.f,0.f,0.f};
    mfma2(acc2, hf[0], hf[1], &W[1][0],    lane);
    mfma2(acc2, hf[2], hf[3], &W[1][8192], lane);

    // logits + softmax (R2-verbatim structure)
    float part[4] = {0.f,0.f,0.f,0.f};
    #pragma unroll
    for (int nt = 0; nt < 8; ++nt) {
      float w3 = aw3r[nt], bb = ab2r[nt];
      #pragma unroll
      for (int rg = 0; rg < 4; ++rg) part[rg] += tanh_fast(acc2[nt][rg] + bb) * w3;
    }
    #pragma unroll
    for (int rg = 0; rg < 4; ++rg) partial[wid*16 + c*4 + rg][rr] = part[rg];
    LDS_FENCE(); BAR();
    if (tid < 96) {
      float s = ab3r;
      #pragma unroll
      for (int cc = 0; cc < 16; ++cc) s += partial[tid][cc];
      attv[tid] = s;
    }
    LDS_FENCE(); BAR();
    if (tid < 16) {
      float l[6]; float m = -1e30f;
      #pragma unroll
      for (int k2 = 0; k2 < 6; ++k2) { l[k2] = attv[tid*6 + k2]; m = fmaxf(m, l[k2]); }
      float ss = 0.f;
      #pragma unroll
      for (int k2 = 0; k2 < 6; ++k2) { l[k2] = __expf(l[k2] - m); ss += l[k2]; }
      float inv = __builtin_amdgcn_rcpf(ss);
      #pragma unroll
      for (int k2 = 0; k2 < 6; ++k2) attv[tid*6 + k2] = l[k2] * inv;
    }
    LDS_FENCE(); BAR();

    // value layer 1 (from ef, still in regs)
    f32x4 acc3[8];
    #pragma unroll
    for (int nt = 0; nt < 8; ++nt) acc3[nt] = (f32x4){0.f,0.f,0.f,0.f};
    mfma2(acc3, ef[0], ef[1], &W[2][0],    lane);
    mfma2(acc3, ef[2], ef[3], &W[2][8192], lane);
    epi_tanh_store(tbuf, acc3, vb1r, wid, lane);
    LDS_FENCE();
    read_h_frags(tbuf, hf, wid, lane);

    // value layer 2
    f32x4 acc4[8];
    #pragma unroll
    for (int nt = 0; nt < 8; ++nt) acc4[nt] = (f32x4){0.f,0.f,0.f,0.f};
    mfma2(acc4, hf[0], hf[1], &W[3][0],    lane);
    mfma2(acc4, hf[2], hf[3], &W[3][8192], lane);

    // val = tanh(acc4+vb2) * att[row] -> swizzled tile (R2-verbatim)
    #pragma unroll
    for (int nt = 0; nt < 8; ++nt) {
      float bb = vb2r[nt];
      #pragma unroll
      for (int rg = 0; rg < 4; ++rg) {
        int brow = wid*16 + c*4 + rg;
        float v = tanh_fast(acc4[nt][rg] + bb) * attv[brow];
        int byte = (brow*256 + (nt*16 + rr)*2) ^ ((brow & 7) << 4);
        *(f16*)(tbuf + byte) = (f16)v;
      }
    }
    LDS_FENCE(); BAR();

    // out[b] = sum_k weighted val rows (R2-verbatim)
    int b0 = t*16;
    for (int i2 = tid; i2 < 2048; i2 += 384) {
      int b = i2 >> 7, col = i2 & 127;
      float s = 0.f;
      #pragma unroll
      for (int k2 = 0; k2 < 6; ++k2) {
        int brow = b*6 + k2;
        int byte = (brow*256 + col*2) ^ ((brow & 7) << 4);
        s += (float)*(const f16*)(tbuf + byte);
      }
      out[(size_t)(b0 + b)*128 + col] = s;
    }
    LDS_FENCE(); BAR();                                  // tbuf free for next stage

    #pragma unroll
    for (int kc = 0; kc < 4; ++kc) ef[kc] = efn[kc];
  }
}

// ---------------- host launcher ----------------
extern "C" void kernel_launch(void* const* d_in, const int* in_sizes, int n_in,
                              void* d_out, int out_size, void* d_ws, size_t ws_size,
                              hipStream_t stream)
{
  const float* self_obs = (const float*)d_in[0];
  const float* obs  = (const float*)d_in[1];
  const float* e_w1 = (const float*)d_in[2];
  const float* e_b1 = (const float*)d_in[3];
  const float* e_w2 = (const float*)d_in[4];
  const float* e_b2 = (const float*)d_in[5];
  const float* v_w1 = (const float*)d_in[6];
  const float* v_b1 = (const float*)d_in[7];
  const float* v_w2 = (const float*)d_in[8];
  const float* v_b2 = (const float*)d_in[9];
  const float* a_w1 = (const float*)d_in[10];
  const float* a_b1 = (const float*)d_in[11];
  const float* a_w2 = (const float*)d_in[12];
  const float* a_b2 = (const float*)d_in[13];
  const float* a_w3 = (const float*)d_in[14];
  const float* a_b3 = (const float*)d_in[15];

  f16*   wfrag = (f16*)d_ws;
  f16*   emb   = (f16*)((char*)d_ws + EMB_BYTE_OFF);
  f16*   meanh = (f16*)((char*)d_ws + MEANH_BYTE_OFF);
  float* out   = (float*)d_out;

  prep_weights<<<400, 256, 0, stream>>>(e_w1, e_w2, v_w1, v_w2, a_w1, a_w2, wfrag);
  enc_kernel<<<256, 384, 0, stream>>>(self_obs, obs, e_b1, e_b2, a_b1, wfrag, emb, meanh);
  att_kernel<<<256, 384, 0, stream>>>(wfrag, emb, meanh, a_b2, a_w3, a_b3, v_b1, v_b2, out);
}

// Round 7
// 332.141 us; speedup vs baseline: 1.3522x; 1.0997x over previous
//
#include <hip/hip_runtime.h>

typedef _Float16 f16;
typedef f16   f16x8 __attribute__((ext_vector_type(8)));
typedef float f32x4 __attribute__((ext_vector_type(4)));
typedef unsigned int uint;

#define NB     65536
#define TPB    16        // att tiles per persistent block (4096/256)

// ---- weight-fragment array in d_ws (f16 element offsets) ----
// frag linear index: ((kc*8 + nt)*64 + lane)*8 + j ; k = kc*32 + (lane>>4)*8 + j ; n = nt*16 + (lane&15)
#define OFF_E1 0        // e_w1 24x128 pad->32x128 : 4096 f16 (8 KB)
#define OFF_E2 4096     // e_w2 128x128 : 16384 f16 (32 KB)
#define OFF_V1 20480
#define OFF_V2 36864
#define OFF_A1 53248    // a_w1 256x128 : 32768 (kc0-3 emb half, kc4-7 mean half)
#define OFF_A2 86016
#define WFRAG_TOTAL 102400

#define EMB_BYTE_OFF   204800ull                       // NROWS x 128 f16
#define PERM_BYTE_OFF  (204800ull + 100663296ull)      // NB x 128 f16: perm[m][rr*8+nt] = meanh1[m][nt*16+rr]

#define LDS_FENCE() asm volatile("s_waitcnt lgkmcnt(0)" ::: "memory")
#define WAIT_VM0()  asm volatile("s_waitcnt vmcnt(0)" ::: "memory")
#define BAR()       { __builtin_amdgcn_s_barrier(); __builtin_amdgcn_sched_barrier(0); }
#define SBAR()      __builtin_amdgcn_sched_barrier(0)

__device__ __forceinline__ float tanh_fast(float x) {
  float e = __expf(2.0f * x);
  return 1.0f - 2.0f * __builtin_amdgcn_rcpf(e + 1.0f);
}

// ---------------- prep: f32 weights -> f16 fragment order (verbatim) ----------------
__global__ void prep_weights(const float* __restrict__ e1, const float* __restrict__ e2,
                             const float* __restrict__ v1, const float* __restrict__ v2,
                             const float* __restrict__ a1, const float* __restrict__ a2,
                             f16* __restrict__ dst)
{
  int i = blockIdx.x * 256 + threadIdx.x;
  if (i >= WFRAG_TOTAL) return;
  const float* src; int base, Ksrc;
  if      (i < OFF_E2) { src = e1; base = OFF_E1; Ksrc = 24;  }
  else if (i < OFF_V1) { src = e2; base = OFF_E2; Ksrc = 128; }
  else if (i < OFF_V2) { src = v1; base = OFF_V1; Ksrc = 128; }
  else if (i < OFF_A1) { src = v2; base = OFF_V2; Ksrc = 128; }
  else if (i < OFF_A2) { src = a1; base = OFF_A1; Ksrc = 256; }
  else                 { src = a2; base = OFF_A2; Ksrc = 128; }
  int li   = i - base;
  int j    = li & 7;
  int lane = (li >> 3) & 63;
  int nt   = (li >> 9) & 7;
  int kc   = li >> 12;
  int k = kc*32 + (lane >> 4)*8 + j;
  int n = nt*16 + (lane & 15);
  float v = (k < Ksrc) ? src[k*128 + n] : 0.0f;
  dst[i] = (f16)v;
}

// ---------------- shared helpers (R4/R5-proven) ----------------
__device__ __forceinline__ void mfma2(f32x4* acc, f16x8 a0, f16x8 a1, const f16* Wb, int lane)
{
  #pragma unroll
  for (int nt = 0; nt < 8; ++nt) {
    f16x8 w = *(const f16x8*)(Wb + (nt*64 + lane)*8);
    acc[nt] = __builtin_amdgcn_mfma_f32_16x16x32_f16(a0, w, acc[nt], 0, 0, 0);
  }
  #pragma unroll
  for (int nt = 0; nt < 8; ++nt) {
    f16x8 w = *(const f16x8*)(Wb + ((8+nt)*64 + lane)*8);
    acc[nt] = __builtin_amdgcn_mfma_f32_16x16x32_f16(a1, w, acc[nt], 0, 0, 0);
  }
}

// tanh(acc + bias8[nt]) -> swizzled f16 tile rows [wid*16, wid*16+16)
__device__ __forceinline__ void epi_tanh_store(char* tb, const f32x4* acc, const float* bias8,
                                               int wid, int lane)
{
  int col0 = lane & 15, q = lane >> 4;
  #pragma unroll
  for (int nt = 0; nt < 8; ++nt) {
    #pragma unroll
    for (int rg = 0; rg < 4; ++rg) {
      int row = wid*16 + q*4 + rg;          // C/D: col=lane&15, row=(lane>>4)*4+rg
      float h = tanh_fast(acc[nt][rg] + bias8[nt]);
      int byte = (row*256 + (nt*16 + col0)*2) ^ ((row & 7) << 4);
      *(f16*)(tb + byte) = (f16)h;
    }
  }
}

__device__ __forceinline__ void read_h_frags(const char* tb, f16x8* frag, int wid, int lane)
{
  int c = lane >> 4, rr = lane & 15;
  int row = wid*16 + rr;                    // A: row=lane&15, k=(lane>>4)*8+j
  #pragma unroll
  for (int kc = 0; kc < 4; ++kc) {
    int byte = (row*256 + kc*64 + c*16) ^ ((row & 7) << 4);
    frag[kc] = *(const f16x8*)(tb + byte);
  }
}

__device__ __forceinline__ void gload_lds16(const f16* g, f16* l) {
  __builtin_amdgcn_global_load_lds(
    (const __attribute__((address_space(1))) unsigned int*)g,
    (__attribute__((address_space(3))) unsigned int*)l, 16, 0, 0);
}
// 32 KB stage with 384 threads: 6 ops (wrap duplicates benign)
__device__ __forceinline__ void stage32(const f16* g, f16* l, int tid) {
  #pragma unroll
  for (int it = 0; it < 6; ++it) {
    int idx = (tid + it*384) & 2047;
    gload_lds16(g + idx*8, l + idx*8);
  }
}
__device__ __forceinline__ void stageE1(const f16* g, f16* l, int tid) {
  #pragma unroll
  for (int it = 0; it < 2; ++it) {
    int idx = (tid + it*384) & 511;
    gload_lds16(g + idx*8, l + idx*8);
  }
}

// R5-verbatim input gather
__device__ __forceinline__ f16x8 gather_x(const float* __restrict__ so, const float* __restrict__ obs,
                                          int r, int c)
{
  int rs = r & (NB - 1);
  uint rq = (uint)r / 6u;
  uint rm = (uint)r - rq*6u;
  float xv[8] = {0.f,0.f,0.f,0.f,0.f,0.f,0.f,0.f};
  if (c == 0) {
    #pragma unroll
    for (int j = 0; j < 8; ++j) xv[j] = so[rs*18 + j];
  } else if (c == 1) {
    #pragma unroll
    for (int j = 0; j < 8; ++j) xv[j] = so[rs*18 + 8 + j];
  } else if (c == 2) {
    xv[0] = so[rs*18 + 16];
    xv[1] = so[rs*18 + 17];
    const float* nb = obs + (size_t)rq*54 + 18 + rm*6;
    #pragma unroll
    for (int j = 0; j < 6; ++j) xv[2+j] = nb[j];
  } // c==3: zero pad
  f16x8 f;
  #pragma unroll
  for (int j = 0; j < 8; ++j) f[j] = (f16)xv[j];
  return f;
}

// ---------------- kernel A: encoder, 6-tile super-blocks + batched A1m mean pass ----------------
__global__ void __launch_bounds__(384, 1) enc_kernel(
  const float* __restrict__ self_obs, const float* __restrict__ obs,
  const float* __restrict__ e_b1, const float* __restrict__ e_b2,
  const float* __restrict__ a_b1,
  const f16* __restrict__ wfrag, f16* __restrict__ emb_out, f16* __restrict__ perm_out)
{
  __shared__ __align__(16) f16 E1b[4096];     //  8 KB resident
  __shared__ __align__(16) f16 E2b[16384];    // 32 KB resident
  __shared__ __align__(16) f16 A1m[16384];    // 32 KB resident (a_w1 mean half)
  __shared__ __align__(16) char tbuf[24576];  // 96x128 f16 swizzled (per-tile work)
  __shared__ __align__(16) char mbuf[24576];  // 96x128 f16 swizzled (super's 96 group means)

  int tid = threadIdx.x, lane = tid & 63, wid = tid >> 6;
  int c = lane >> 4, rr = lane & 15;

  stageE1(wfrag + OFF_E1, E1b, tid);
  stage32(wfrag + OFF_E2, E2b, tid);
  stage32(wfrag + OFF_A1 + 16384, A1m, tid);

  float eb1r[8], eb2r[8], ab1r[8];
  #pragma unroll
  for (int nt = 0; nt < 8; ++nt) {
    int col = nt*16 + rr;
    eb1r[nt] = e_b1[col]; eb2r[nt] = e_b2[col]; ab1r[nt] = a_b1[col];
  }

  int S = blockIdx.x;                          // super index (683 supers of 6 tiles)
  int T0 = S*6;
  int jmax = 4096 - T0; if (jmax > 6) jmax = 6;

  f16x8 xfrag = gather_x(self_obs, obs, T0*96 + wid*16 + rr, c);
  WAIT_VM0(); BAR();

  for (int j = 0; j < jmax; ++j) {
    int T = T0 + j;
    // ---- enc layer 1 (K=32) ----
    f32x4 acc1[8];
    #pragma unroll
    for (int nt = 0; nt < 8; ++nt) acc1[nt] = (f32x4){0.f,0.f,0.f,0.f};
    #pragma unroll
    for (int nt = 0; nt < 8; ++nt) {
      f16x8 w = *(const f16x8*)(E1b + (nt*64 + lane)*8);
      acc1[nt] = __builtin_amdgcn_mfma_f32_16x16x32_f16(xfrag, w, acc1[nt], 0, 0, 0);
    }
    epi_tanh_store(tbuf, acc1, eb1r, wid, lane);
    LDS_FENCE();
    f16x8 hf[4];
    read_h_frags(tbuf, hf, wid, lane);

    // prefetch next tile's input
    f16x8 xnext = xfrag;
    if (j + 1 < jmax) xnext = gather_x(self_obs, obs, (T+1)*96 + wid*16 + rr, c);

    // ---- enc layer 2 (K=128) ----
    f32x4 acc2[8];
    #pragma unroll
    for (int nt = 0; nt < 8; ++nt) acc2[nt] = (f32x4){0.f,0.f,0.f,0.f};
    mfma2(acc2, hf[0], hf[1], E2b,        lane);
    mfma2(acc2, hf[2], hf[3], E2b + 8192, lane);
    epi_tanh_store(tbuf, acc2, eb2r, wid, lane);   // emb tile
    LDS_FENCE();

    // emb -> global, wave-local rows (no barrier needed)
    {
      size_t gbase = (size_t)T * (96*128);
      #pragma unroll
      for (int it = 0; it < 4; ++it) {
        int idx = it*64 + lane;                    // 256 chunks per stripe
        int row = wid*16 + (idx >> 4), ch = idx & 15;
        int byte = (row*256 + ch*16) ^ ((row & 7) << 4);
        *(uint4*)(emb_out + gbase + (size_t)row*128 + ch*8) = *(const uint4*)(tbuf + byte);
      }
    }
    BAR();                                         // all stripes' emb in tbuf visible
    // group means (packed f16x2) -> mbuf rows j*16..j*16+15
    for (int i2 = tid; i2 < 1024; i2 += 384) {
      int b = i2 >> 6, cp = i2 & 63;
      float s0 = 0.f, s1 = 0.f;
      #pragma unroll
      for (int k2 = 0; k2 < 6; ++k2) {
        int brow = b*6 + k2;
        uint v = *(const uint*)(tbuf + ((brow*256 + cp*4) ^ ((brow & 7) << 4)));
        s0 += (float)__builtin_bit_cast(f16, (unsigned short)(v & 0xffff));
        s1 += (float)__builtin_bit_cast(f16, (unsigned short)(v >> 16));
      }
      f16 h0 = (f16)(s0 * (1.0f/6.0f)), h1 = (f16)(s1 * (1.0f/6.0f));
      uint mv = (uint)__builtin_bit_cast(unsigned short, h0)
              | ((uint)__builtin_bit_cast(unsigned short, h1) << 16);
      int mrow = j*16 + b;
      *(uint*)(mbuf + ((mrow*256 + cp*4) ^ ((mrow & 7) << 4))) = mv;
    }
    LDS_FENCE(); BAR();                            // tbuf free for next tile; mbuf row-block done
    xfrag = xnext;
  }

  // ---- batched A1m pass over 96 mean rows ----
  f16x8 mfr[4];
  read_h_frags(mbuf, mfr, wid, lane);
  f32x4 accm[8];
  #pragma unroll
  for (int nt = 0; nt < 8; ++nt) accm[nt] = (f32x4){0.f,0.f,0.f,0.f};
  mfma2(accm, mfr[0], mfr[1], A1m,        lane);
  mfma2(accm, mfr[2], mfr[3], A1m + 8192, lane);

  // meanh1 = accm + a_b1 -> perm layout: perm[m][rr*8+nt], 4 x 16B stores per lane
  int gbase = S*96;
  #pragma unroll
  for (int rg = 0; rg < 4; ++rg) {
    int m = gbase + wid*16 + c*4 + rg;
    if (m < NB) {
      f16x8 v;
      #pragma unroll
      for (int nt = 0; nt < 8; ++nt) v[nt] = (f16)(accm[nt][rg] + ab1r[nt]);
      *(f16x8*)(perm_out + (size_t)m*128 + rr*8) = v;
    }
  }
}

// ---------------- kernel B: att+val, resident weights, reg-prefetched emb/meanh frags ----------------
__global__ void __launch_bounds__(384, 1) att_kernel(
  const f16* __restrict__ wfrag, const f16* __restrict__ emb, const f16* __restrict__ perm,
  const float* __restrict__ a_b2, const float* __restrict__ a_w3, const float* __restrict__ a_b3,
  const float* __restrict__ v_b1, const float* __restrict__ v_b2,
  float* __restrict__ out)
{
  __shared__ __align__(16) f16 W[4][16384];   // A1emb, A2, V1, V2 : 128 KB resident
  __shared__ __align__(16) char tbuf[24576];
  __shared__ float attv[96];

  int tid = threadIdx.x, lane = tid & 63, wid = tid >> 6;
  int c = lane >> 4, rr = lane & 15;

  stage32(wfrag + OFF_A1, &W[0][0], tid);
  stage32(wfrag + OFF_A2, &W[1][0], tid);
  stage32(wfrag + OFF_V1, &W[2][0], tid);
  stage32(wfrag + OFF_V2, &W[3][0], tid);

  float ab2r[8], aw3r[8], vb1r[8], vb2r[8];
  #pragma unroll
  for (int nt = 0; nt < 8; ++nt) {
    int col = nt*16 + rr;
    ab2r[nt] = a_b2[col]; aw3r[nt] = a_w3[col]; vb1r[nt] = v_b1[col]; vb2r[nt] = v_b2[col];
  }
  float ab3r = a_b3[0];

  int t0 = blockIdx.x * TPB;
  // prefetch tile t0: emb A-frags + meanh1 C-frags
  f16x8 ef[4], mh[4];
  {
    size_t r = (size_t)t0*96 + wid*16 + rr;
    #pragma unroll
    for (int kc = 0; kc < 4; ++kc) ef[kc] = *(const f16x8*)(emb + r*128 + kc*32 + c*8);
    #pragma unroll
    for (int rg = 0; rg < 4; ++rg) {
      int m = (t0*96 + wid*16 + c*4 + rg) & (NB - 1);
      mh[rg] = *(const f16x8*)(perm + (size_t)m*128 + rr*8);
    }
  }
  WAIT_VM0(); BAR();

  for (int i = 0; i < TPB; ++i) {
    int t = t0 + i;

    // ---- att layer 1: emb @ A1emb ----
    f32x4 acc3[8];
    #pragma unroll
    for (int nt = 0; nt < 8; ++nt) acc3[nt] = (f32x4){0.f,0.f,0.f,0.f};
    mfma2(acc3, ef[0], ef[1], &W[0][0],    lane);
    mfma2(acc3, ef[2], ef[3], &W[0][8192], lane);

    // prefetch t+1 frags (consumed next iteration; compiler-inserted waits)
    f16x8 efn[4], mhn[4];
    {
      int tn = (i+1 < TPB) ? (t+1) : t;
      size_t r = (size_t)tn*96 + wid*16 + rr;
      #pragma unroll
      for (int kc = 0; kc < 4; ++kc) efn[kc] = *(const f16x8*)(emb + r*128 + kc*32 + c*8);
      #pragma unroll
      for (int rg = 0; rg < 4; ++rg) {
        int m = (tn*96 + wid*16 + c*4 + rg) & (NB - 1);
        mhn[rg] = *(const f16x8*)(perm + (size_t)m*128 + rr*8);
      }
    }

    // L1 epilogue: h1 = tanh(acc3 + meanh1[r % B]) -> tbuf (wave-private rows)
    #pragma unroll
    for (int nt = 0; nt < 8; ++nt) {
      #pragma unroll
      for (int rg = 0; rg < 4; ++rg) {
        int row = wid*16 + c*4 + rg;
        float h = tanh_fast(acc3[nt][rg] + (float)mh[rg][nt]);
        int byte = (row*256 + (nt*16 + rr)*2) ^ ((row & 7) << 4);
        *(f16*)(tbuf + byte) = (f16)h;
      }
    }
    LDS_FENCE();
    f16x8 hf[4];
    read_h_frags(tbuf, hf, wid, lane);

    // ---- att layer 2 ----
    f32x4 acc4[8];
    #pragma unroll
    for (int nt = 0; nt < 8; ++nt) acc4[nt] = (f32x4){0.f,0.f,0.f,0.f};
    mfma2(acc4, hf[0], hf[1], &W[1][0],    lane);
    mfma2(acc4, hf[2], hf[3], &W[1][8192], lane);

    // logits: per-lane partials + 16-lane shuffle reduce (lanes same (c,rg) = same row)
    float part[4] = {0.f,0.f,0.f,0.f};
    #pragma unroll
    for (int nt = 0; nt < 8; ++nt) {
      #pragma unroll
      for (int rg = 0; rg < 4; ++rg) part[rg] += tanh_fast(acc4[nt][rg] + ab2r[nt]) * aw3r[nt];
    }
    #pragma unroll
    for (int rg = 0; rg < 4; ++rg) {
      part[rg] += __shfl_xor(part[rg], 1);
      part[rg] += __shfl_xor(part[rg], 2);
      part[rg] += __shfl_xor(part[rg], 4);
      part[rg] += __shfl_xor(part[rg], 8);
    }
    if (rr == 0) {
      #pragma unroll
      for (int rg = 0; rg < 4; ++rg) attv[wid*16 + c*4 + rg] = part[rg] + ab3r;
    }
    LDS_FENCE(); BAR();
    if (tid < 16) {                               // softmax over each group's 6 rows
      float l[6]; float m = -1e30f;
      #pragma unroll
      for (int k2 = 0; k2 < 6; ++k2) { l[k2] = attv[tid*6 + k2]; m = fmaxf(m, l[k2]); }
      float ss = 0.f;
      #pragma unroll
      for (int k2 = 0; k2 < 6; ++k2) { l[k2] = __expf(l[k2] - m); ss += l[k2]; }
      float inv = __builtin_amdgcn_rcpf(ss);
      #pragma unroll
      for (int k2 = 0; k2 < 6; ++k2) attv[tid*6 + k2] = l[k2] * inv;
    }
    LDS_FENCE(); BAR();
    float attw[4];
    #pragma unroll
    for (int rg = 0; rg < 4; ++rg) attw[rg] = attv[wid*16 + c*4 + rg];

    // ---- value layer 1 (ef still in regs) ----
    f32x4 acc5[8];
    #pragma unroll
    for (int nt = 0; nt < 8; ++nt) acc5[nt] = (f32x4){0.f,0.f,0.f,0.f};
    mfma2(acc5, ef[0], ef[1], &W[2][0],    lane);
    mfma2(acc5, ef[2], ef[3], &W[2][8192], lane);
    epi_tanh_store(tbuf, acc5, vb1r, wid, lane);
    LDS_FENCE();
    read_h_frags(tbuf, hf, wid, lane);

    // ---- value layer 2 ----
    f32x4 acc6[8];
    #pragma unroll
    for (int nt = 0; nt < 8; ++nt) acc6[nt] = (f32x4){0.f,0.f,0.f,0.f};
    mfma2(acc6, hf[0], hf[1], &W[3][0],    lane);
    mfma2(acc6, hf[2], hf[3], &W[3][8192], lane);

    // val = tanh(acc6+vb2)*att -> swizzled tile
    #pragma unroll
    for (int nt = 0; nt < 8; ++nt) {
      #pragma unroll
      for (int rg = 0; rg < 4; ++rg) {
        int brow = wid*16 + c*4 + rg;
        float v = tanh_fast(acc6[nt][rg] + vb2r[nt]) * attw[rg];
        int byte = (brow*256 + (nt*16 + rr)*2) ^ ((brow & 7) << 4);
        *(f16*)(tbuf + byte) = (f16)v;
      }
    }
    LDS_FENCE(); BAR();

    // out[b] = sum of 6 weighted rows (packed f16x2 reads, float2 stores)
    int b0 = t*16;
    for (int i2 = tid; i2 < 1024; i2 += 384) {
      int b = i2 >> 6, cp = i2 & 63;
      float s0 = 0.f, s1 = 0.f;
      #pragma unroll
      for (int k2 = 0; k2 < 6; ++k2) {
        int brow = b*6 + k2;
        uint v = *(const uint*)(tbuf + ((brow*256 + cp*4) ^ ((brow & 7) << 4)));
        s0 += (float)__builtin_bit_cast(f16, (unsigned short)(v & 0xffff));
        s1 += (float)__builtin_bit_cast(f16, (unsigned short)(v >> 16));
      }
      float2 st = {s0, s1};
      *(float2*)(out + (size_t)(b0 + b)*128 + cp*2) = st;
    }
    BAR();                                        // tbuf free for next tile

    #pragma unroll
    for (int kc = 0; kc < 4; ++kc) ef[kc] = efn[kc];
    #pragma unroll
    for (int rg = 0; rg < 4; ++rg) mh[rg] = mhn[rg];
  }
}

// ---------------- host launcher ----------------
extern "C" void kernel_launch(void* const* d_in, const int* in_sizes, int n_in,
                              void* d_out, int out_size, void* d_ws, size_t ws_size,
                              hipStream_t stream)
{
  const float* self_obs = (const float*)d_in[0];
  const float* obs  = (const float*)d_in[1];
  const float* e_w1 = (const float*)d_in[2];
  const float* e_b1 = (const float*)d_in[3];
  const float* e_w2 = (const float*)d_in[4];
  const float* e_b2 = (const float*)d_in[5];
  const float* v_w1 = (const float*)d_in[6];
  const float* v_b1 = (const float*)d_in[7];
  const float* v_w2 = (const float*)d_in[8];
  const float* v_b2 = (const float*)d_in[9];
  const float* a_w1 = (const float*)d_in[10];
  const float* a_b1 = (const float*)d_in[11];
  const float* a_w2 = (const float*)d_in[12];
  const float* a_b2 = (const float*)d_in[13];
  const float* a_w3 = (const float*)d_in[14];
  const float* a_b3 = (const float*)d_in[15];

  f16*   wfrag = (f16*)d_ws;
  f16*   emb   = (f16*)((char*)d_ws + EMB_BYTE_OFF);
  f16*   perm  = (f16*)((char*)d_ws + PERM_BYTE_OFF);
  float* out   = (float*)d_out;

  prep_weights<<<400, 256, 0, stream>>>(e_w1, e_w2, v_w1, v_w2, a_w1, a_w2, wfrag);
  enc_kernel<<<683, 384, 0, stream>>>(self_obs, obs, e_b1, e_b2, a_b1, wfrag, emb, perm);
  att_kernel<<<256, 384, 0, stream>>>(wfrag, emb, perm, a_b2, a_w3, a_b3, v_b1, v_b2, out);
}

// Round 8
// 304.726 us; speedup vs baseline: 1.4738x; 1.0900x over previous
//
#include <hip/hip_runtime.h>

typedef _Float16 f16;
typedef f16   f16x8 __attribute__((ext_vector_type(8)));
typedef float f32x4 __attribute__((ext_vector_type(4)));
typedef unsigned int uint;

#define NB     65536
#define TPB    16        // (enc) tiles per... enc uses 6-tile supers; att uses wave-jobs

// ---- weight-fragment array in d_ws (f16 element offsets) ----
// frag linear index: ((kc*8 + nt)*64 + lane)*8 + j ; k = kc*32 + (lane>>4)*8 + j ; n = nt*16 + (lane&15)
#define OFF_E1 0
#define OFF_E2 4096
#define OFF_V1 20480
#define OFF_V2 36864
#define OFF_A1 53248    // a_w1 256x128 (kc0-3 emb half, kc4-7 mean half)
#define OFF_A2 86016
#define WFRAG_TOTAL 102400

#define EMB_BYTE_OFF   204800ull                       // NROWS x 128 f16
#define PERM_BYTE_OFF  (204800ull + 100663296ull)      // NB x 128 f16: perm[m][rr*8+nt] = meanh1[m][nt*16+rr]

#define LDS_FENCE() asm volatile("s_waitcnt lgkmcnt(0)" ::: "memory")
#define WAIT_VM0()  asm volatile("s_waitcnt vmcnt(0)" ::: "memory")
#define BAR()       { __builtin_amdgcn_s_barrier(); __builtin_amdgcn_sched_barrier(0); }

__device__ __forceinline__ float tanh_fast(float x) {
  float e = __expf(2.0f * x);
  return 1.0f - 2.0f * __builtin_amdgcn_rcpf(e + 1.0f);
}

// ---------------- prep: f32 weights -> f16 fragment order (verbatim) ----------------
__global__ void prep_weights(const float* __restrict__ e1, const float* __restrict__ e2,
                             const float* __restrict__ v1, const float* __restrict__ v2,
                             const float* __restrict__ a1, const float* __restrict__ a2,
                             f16* __restrict__ dst)
{
  int i = blockIdx.x * 256 + threadIdx.x;
  if (i >= WFRAG_TOTAL) return;
  const float* src; int base, Ksrc;
  if      (i < OFF_E2) { src = e1; base = OFF_E1; Ksrc = 24;  }
  else if (i < OFF_V1) { src = e2; base = OFF_E2; Ksrc = 128; }
  else if (i < OFF_V2) { src = v1; base = OFF_V1; Ksrc = 128; }
  else if (i < OFF_A1) { src = v2; base = OFF_V2; Ksrc = 128; }
  else if (i < OFF_A2) { src = a1; base = OFF_A1; Ksrc = 256; }
  else                 { src = a2; base = OFF_A2; Ksrc = 128; }
  int li   = i - base;
  int j    = li & 7;
  int lane = (li >> 3) & 63;
  int nt   = (li >> 9) & 7;
  int kc   = li >> 12;
  int k = kc*32 + (lane >> 4)*8 + j;
  int n = nt*16 + (lane & 15);
  float v = (k < Ksrc) ? src[k*128 + n] : 0.0f;
  dst[i] = (f16)v;
}

// ---------------- shared helpers ----------------
__device__ __forceinline__ void mfma2(f32x4* acc, f16x8 a0, f16x8 a1, const f16* Wb, int lane)
{
  #pragma unroll
  for (int nt = 0; nt < 8; ++nt) {
    f16x8 w = *(const f16x8*)(Wb + (nt*64 + lane)*8);
    acc[nt] = __builtin_amdgcn_mfma_f32_16x16x32_f16(a0, w, acc[nt], 0, 0, 0);
  }
  #pragma unroll
  for (int nt = 0; nt < 8; ++nt) {
    f16x8 w = *(const f16x8*)(Wb + ((8+nt)*64 + lane)*8);
    acc[nt] = __builtin_amdgcn_mfma_f32_16x16x32_f16(a1, w, acc[nt], 0, 0, 0);
  }
}

// tanh(acc + bias8[nt]) -> swizzled f16 tile rows [wid*16, wid*16+16)  (enc)
__device__ __forceinline__ void epi_tanh_store(char* tb, const f32x4* acc, const float* bias8,
                                               int wid, int lane)
{
  int col0 = lane & 15, q = lane >> 4;
  #pragma unroll
  for (int nt = 0; nt < 8; ++nt) {
    #pragma unroll
    for (int rg = 0; rg < 4; ++rg) {
      int row = wid*16 + q*4 + rg;
      float h = tanh_fast(acc[nt][rg] + bias8[nt]);
      int byte = (row*256 + (nt*16 + col0)*2) ^ ((row & 7) << 4);
      *(f16*)(tb + byte) = (f16)h;
    }
  }
}

__device__ __forceinline__ void read_h_frags(const char* tb, f16x8* frag, int wid, int lane)
{
  int c = lane >> 4, rr = lane & 15;
  int row = wid*16 + rr;
  #pragma unroll
  for (int kc = 0; kc < 4; ++kc) {
    int byte = (row*256 + kc*64 + c*16) ^ ((row & 7) << 4);
    frag[kc] = *(const f16x8*)(tb + byte);
  }
}

__device__ __forceinline__ void gload_lds16(const f16* g, f16* l) {
  __builtin_amdgcn_global_load_lds(
    (const __attribute__((address_space(1))) unsigned int*)g,
    (__attribute__((address_space(3))) unsigned int*)l, 16, 0, 0);
}
// enc staging helpers (384 threads)
__device__ __forceinline__ void stage32(const f16* g, f16* l, int tid) {
  #pragma unroll
  for (int it = 0; it < 6; ++it) {
    int idx = (tid + it*384) & 2047;
    gload_lds16(g + idx*8, l + idx*8);
  }
}
__device__ __forceinline__ void stageE1(const f16* g, f16* l, int tid) {
  #pragma unroll
  for (int it = 0; it < 2; ++it) {
    int idx = (tid + it*384) & 511;
    gload_lds16(g + idx*8, l + idx*8);
  }
}

// R5-verbatim input gather
__device__ __forceinline__ f16x8 gather_x(const float* __restrict__ so, const float* __restrict__ obs,
                                          int r, int c)
{
  int rs = r & (NB - 1);
  uint rq = (uint)r / 6u;
  uint rm = (uint)r - rq*6u;
  float xv[8] = {0.f,0.f,0.f,0.f,0.f,0.f,0.f,0.f};
  if (c == 0) {
    #pragma unroll
    for (int j = 0; j < 8; ++j) xv[j] = so[rs*18 + j];
  } else if (c == 1) {
    #pragma unroll
    for (int j = 0; j < 8; ++j) xv[j] = so[rs*18 + 8 + j];
  } else if (c == 2) {
    xv[0] = so[rs*18 + 16];
    xv[1] = so[rs*18 + 17];
    const float* nb = obs + (size_t)rq*54 + 18 + rm*6;
    #pragma unroll
    for (int j = 0; j < 6; ++j) xv[2+j] = nb[j];
  }
  f16x8 f;
  #pragma unroll
  for (int j = 0; j < 8; ++j) f[j] = (f16)xv[j];
  return f;
}

// ---------------- kernel A: encoder (R7 verbatim) ----------------
__global__ void __launch_bounds__(384, 1) enc_kernel(
  const float* __restrict__ self_obs, const float* __restrict__ obs,
  const float* __restrict__ e_b1, const float* __restrict__ e_b2,
  const float* __restrict__ a_b1,
  const f16* __restrict__ wfrag, f16* __restrict__ emb_out, f16* __restrict__ perm_out)
{
  __shared__ __align__(16) f16 E1b[4096];
  __shared__ __align__(16) f16 E2b[16384];
  __shared__ __align__(16) f16 A1m[16384];
  __shared__ __align__(16) char tbuf[24576];
  __shared__ __align__(16) char mbuf[24576];

  int tid = threadIdx.x, lane = tid & 63, wid = tid >> 6;
  int c = lane >> 4, rr = lane & 15;

  stageE1(wfrag + OFF_E1, E1b, tid);
  stage32(wfrag + OFF_E2, E2b, tid);
  stage32(wfrag + OFF_A1 + 16384, A1m, tid);

  float eb1r[8], eb2r[8], ab1r[8];
  #pragma unroll
  for (int nt = 0; nt < 8; ++nt) {
    int col = nt*16 + rr;
    eb1r[nt] = e_b1[col]; eb2r[nt] = e_b2[col]; ab1r[nt] = a_b1[col];
  }

  int S = blockIdx.x;
  int T0 = S*6;
  int jmax = 4096 - T0; if (jmax > 6) jmax = 6;

  f16x8 xfrag = gather_x(self_obs, obs, T0*96 + wid*16 + rr, c);
  WAIT_VM0(); BAR();

  for (int j = 0; j < jmax; ++j) {
    int T = T0 + j;
    f32x4 acc1[8];
    #pragma unroll
    for (int nt = 0; nt < 8; ++nt) acc1[nt] = (f32x4){0.f,0.f,0.f,0.f};
    #pragma unroll
    for (int nt = 0; nt < 8; ++nt) {
      f16x8 w = *(const f16x8*)(E1b + (nt*64 + lane)*8);
      acc1[nt] = __builtin_amdgcn_mfma_f32_16x16x32_f16(xfrag, w, acc1[nt], 0, 0, 0);
    }
    epi_tanh_store(tbuf, acc1, eb1r, wid, lane);
    LDS_FENCE();
    f16x8 hf[4];
    read_h_frags(tbuf, hf, wid, lane);

    f16x8 xnext = xfrag;
    if (j + 1 < jmax) xnext = gather_x(self_obs, obs, (T+1)*96 + wid*16 + rr, c);

    f32x4 acc2[8];
    #pragma unroll
    for (int nt = 0; nt < 8; ++nt) acc2[nt] = (f32x4){0.f,0.f,0.f,0.f};
    mfma2(acc2, hf[0], hf[1], E2b,        lane);
    mfma2(acc2, hf[2], hf[3], E2b + 8192, lane);
    epi_tanh_store(tbuf, acc2, eb2r, wid, lane);
    LDS_FENCE();

    {
      size_t gbase = (size_t)T * (96*128);
      #pragma unroll
      for (int it = 0; it < 4; ++it) {
        int idx = it*64 + lane;
        int row = wid*16 + (idx >> 4), ch = idx & 15;
        int byte = (row*256 + ch*16) ^ ((row & 7) << 4);
        *(uint4*)(emb_out + gbase + (size_t)row*128 + ch*8) = *(const uint4*)(tbuf + byte);
      }
    }
    BAR();
    for (int i2 = tid; i2 < 1024; i2 += 384) {
      int b = i2 >> 6, cp = i2 & 63;
      float s0 = 0.f, s1 = 0.f;
      #pragma unroll
      for (int k2 = 0; k2 < 6; ++k2) {
        int brow = b*6 + k2;
        uint v = *(const uint*)(tbuf + ((brow*256 + cp*4) ^ ((brow & 7) << 4)));
        s0 += (float)__builtin_bit_cast(f16, (unsigned short)(v & 0xffff));
        s1 += (float)__builtin_bit_cast(f16, (unsigned short)(v >> 16));
      }
      f16 h0 = (f16)(s0 * (1.0f/6.0f)), h1 = (f16)(s1 * (1.0f/6.0f));
      uint mv = (uint)__builtin_bit_cast(unsigned short, h0)
              | ((uint)__builtin_bit_cast(unsigned short, h1) << 16);
      int mrow = j*16 + b;
      *(uint*)(mbuf + ((mrow*256 + cp*4) ^ ((mrow & 7) << 4))) = mv;
    }
    LDS_FENCE(); BAR();
    xfrag = xnext;
  }

  f16x8 mfr[4];
  read_h_frags(mbuf, mfr, wid, lane);
  f32x4 accm[8];
  #pragma unroll
  for (int nt = 0; nt < 8; ++nt) accm[nt] = (f32x4){0.f,0.f,0.f,0.f};
  mfma2(accm, mfr[0], mfr[1], A1m,        lane);
  mfma2(accm, mfr[2], mfr[3], A1m + 8192, lane);

  int gbase = S*96;
  #pragma unroll
  for (int rg = 0; rg < 4; ++rg) {
    int m = gbase + wid*16 + c*4 + rg;
    if (m < NB) {
      f16x8 v;
      #pragma unroll
      for (int nt = 0; nt < 8; ++nt) v[nt] = (f16)(accm[nt][rg] + ab1r[nt]);
      *(f16x8*)(perm_out + (size_t)m*128 + rr*8) = v;
    }
  }
}

// ---------------- kernel B: de-lockstepped att+val — wave-local jobs, zero main-loop barriers ----
#define NWAVE  7
#define AITERS 5
#define NJOBS  8192

__global__ void __launch_bounds__(448, 1) att_kernel(
  const f16* __restrict__ wfrag, const f16* __restrict__ emb, const f16* __restrict__ perm,
  const float* __restrict__ a_b2, const float* __restrict__ a_w3,
  const float* __restrict__ v_b1, const float* __restrict__ v_b2,
  float* __restrict__ out)
{
  __shared__ __align__(16) f16 W[4][16384];        // A1emb, A2, V1, V2 resident (128 KB)
  __shared__ __align__(16) char tbuf[NWAVE][4096]; // per-wave private transpose tile

  int tid = threadIdx.x, lane = tid & 63, wid = tid >> 6;
  int c = lane >> 4, rr = lane & 15;

  {
    const int offs[4] = {OFF_A1, OFF_A2, OFF_V1, OFF_V2};
    #pragma unroll
    for (int m = 0; m < 4; ++m) {
      const f16* s = wfrag + offs[m];
      #pragma unroll
      for (int it = 0; it < 5; ++it) {
        int idx = (tid + it*448) & 2047;
        gload_lds16(s + idx*8, &W[m][0] + idx*8);
      }
    }
  }

  float ab2r[8], aw3r[8], vb1r[8], vb2r[8];
  #pragma unroll
  for (int nt = 0; nt < 8; ++nt) {
    int col = nt*16 + rr;
    ab2r[nt] = a_b2[col]; aw3r[nt] = a_w3[col]; vb1r[nt] = v_b1[col]; vb2r[nt] = v_b2[col];
  }

  WAIT_VM0(); BAR();                       // the ONLY barrier — weights resident

  char* tb = (char*)&tbuf[wid][0];

  for (int it = 0; it < AITERS; ++it) {
    int job = (blockIdx.x * AITERS + it) * NWAVE + wid;
    if (job >= NJOBS) break;               // wave-uniform; no barriers below -> safe
    int rbase = job * 48;                  // 8 complete groups of 6 rows

    // ========== pass A: logits for 48 rows (3 chunks of 16) ==========
    f16x8 ef[3][4];
    float E[3][4];
    #pragma unroll
    for (int ch = 0; ch < 3; ++ch) {
      int ra = rbase + ch*16 + rr;
      #pragma unroll
      for (int kc = 0; kc < 4; ++kc)
        ef[ch][kc] = *(const f16x8*)(emb + (size_t)ra*128 + kc*32 + c*8);
      f16x8 mh[4];
      #pragma unroll
      for (int rg = 0; rg < 4; ++rg) {
        int m = (rbase + ch*16 + c*4 + rg) & (NB - 1);   // reference quirk: r % B
        mh[rg] = *(const f16x8*)(perm + (size_t)m*128 + rr*8);
      }
      f32x4 acc[8];
      #pragma unroll
      for (int nt = 0; nt < 8; ++nt) acc[nt] = (f32x4){0.f,0.f,0.f,0.f};
      mfma2(acc, ef[ch][0], ef[ch][1], &W[0][0],    lane);
      mfma2(acc, ef[ch][2], ef[ch][3], &W[0][8192], lane);
      // h1 = tanh(acc + meanh1) -> wave tile (local rows 0-15)
      #pragma unroll
      for (int nt = 0; nt < 8; ++nt) {
        #pragma unroll
        for (int rg = 0; rg < 4; ++rg) {
          int row = c*4 + rg;
          float h = tanh_fast(acc[nt][rg] + (float)mh[rg][nt]);
          *(f16*)(tb + ((row*256 + (nt*16 + rr)*2) ^ ((row & 7) << 4))) = (f16)h;
        }
      }
      LDS_FENCE();
      f16x8 hf[4];
      #pragma unroll
      for (int kc = 0; kc < 4; ++kc)
        hf[kc] = *(const f16x8*)(tb + ((rr*256 + kc*64 + c*16) ^ ((rr & 7) << 4)));
      f32x4 acc2[8];
      #pragma unroll
      for (int nt = 0; nt < 8; ++nt) acc2[nt] = (f32x4){0.f,0.f,0.f,0.f};
      mfma2(acc2, hf[0], hf[1], &W[1][0],    lane);
      mfma2(acc2, hf[2], hf[3], &W[1][8192], lane);
      float part[4] = {0.f,0.f,0.f,0.f};
      #pragma unroll
      for (int nt = 0; nt < 8; ++nt) {
        #pragma unroll
        for (int rg = 0; rg < 4; ++rg)
          part[rg] += tanh_fast(acc2[nt][rg] + ab2r[nt]) * aw3r[nt];
      }
      #pragma unroll
      for (int rg = 0; rg < 4; ++rg) {
        part[rg] += __shfl_xor(part[rg], 1);
        part[rg] += __shfl_xor(part[rg], 2);
        part[rg] += __shfl_xor(part[rg], 4);
        part[rg] += __shfl_xor(part[rg], 8);
        E[ch][rg] = __expf(part[rg]);      // a_b3 cancels in softmax; |logit|<=~9 so no max-sub
      }
    }

    // ========== register-only softmax over the wave's 8 groups ==========
    int g = rr & 7;                        // lanes rr>=8 duplicate groups 0-7 (harmless)
    float pg = 0.f;
    #pragma unroll
    for (int ch = 0; ch < 3; ++ch) {
      #pragma unroll
      for (int rg = 0; rg < 4; ++rg) {
        int r = ch*16 + c*4 + rg;          // c runtime -> VALU compare
        pg += (r/6 == g) ? E[ch][rg] : 0.f;
      }
    }
    pg += __shfl_xor(pg, 16);
    pg += __shfl_xor(pg, 32);              // all clusters summed: S_g on lanes with rr&7==g
    float invS = __builtin_amdgcn_rcpf(pg);
    float attw[3][4];
    #pragma unroll
    for (int ch = 0; ch < 3; ++ch) {
      #pragma unroll
      for (int rg = 0; rg < 4; ++rg) {
        int r = ch*16 + c*4 + rg;
        attw[ch][rg] = E[ch][rg] * __shfl(invS, r/6);   // lane r/6 (cluster 0) holds invS_g
      }
    }

    // ========== pass B: value MLP + weighted group sums ==========
    float o0x=0.f,o0y=0.f,o1x=0.f,o1y=0.f,o2x=0.f,o2y=0.f,o3x=0.f,o3y=0.f;
    float o4x=0.f,o4y=0.f,o5x=0.f,o5y=0.f,o6x=0.f,o6y=0.f,o7x=0.f,o7y=0.f;
    #pragma unroll
    for (int ch = 0; ch < 3; ++ch) {
      f32x4 acc3[8];
      #pragma unroll
      for (int nt = 0; nt < 8; ++nt) acc3[nt] = (f32x4){0.f,0.f,0.f,0.f};
      mfma2(acc3, ef[ch][0], ef[ch][1], &W[2][0],    lane);
      mfma2(acc3, ef[ch][2], ef[ch][3], &W[2][8192], lane);
      #pragma unroll
      for (int nt = 0; nt < 8; ++nt) {
        #pragma unroll
        for (int rg = 0; rg < 4; ++rg) {
          int row = c*4 + rg;
          float h = tanh_fast(acc3[nt][rg] + vb1r[nt]);
          *(f16*)(tb + ((row*256 + (nt*16 + rr)*2) ^ ((row & 7) << 4))) = (f16)h;
        }
      }
      LDS_FENCE();
      f16x8 hf[4];
      #pragma unroll
      for (int kc = 0; kc < 4; ++kc)
        hf[kc] = *(const f16x8*)(tb + ((rr*256 + kc*64 + c*16) ^ ((rr & 7) << 4)));
      f32x4 acc4[8];
      #pragma unroll
      for (int nt = 0; nt < 8; ++nt) acc4[nt] = (f32x4){0.f,0.f,0.f,0.f};
      mfma2(acc4, hf[0], hf[1], &W[3][0],    lane);
      mfma2(acc4, hf[2], hf[3], &W[3][8192], lane);
      // val = tanh(acc4+vb2)*attw -> wave tile
      #pragma unroll
      for (int nt = 0; nt < 8; ++nt) {
        #pragma unroll
        for (int rg = 0; rg < 4; ++rg) {
          int row = c*4 + rg;
          float v = tanh_fast(acc4[nt][rg] + vb2r[nt]) * attw[ch][rg];
          *(f16*)(tb + ((row*256 + (nt*16 + rr)*2) ^ ((row & 7) << 4))) = (f16)v;
        }
      }
      LDS_FENCE();
      // group-accumulate: lane owns col pair {2*lane, 2*lane+1}; group index compile-time
      #pragma unroll
      for (int rl = 0; rl < 16; ++rl) {
        uint v = *(const uint*)(tb + ((rl*256 + lane*4) ^ ((rl & 7) << 4)));
        float lo = (float)__builtin_bit_cast(f16, (unsigned short)(v & 0xffff));
        float hi = (float)__builtin_bit_cast(f16, (unsigned short)(v >> 16));
        constexpr int gmap0[16] = {0,0,0,0,0,0,1,1,1,1,1,1,2,2,2,2};
        constexpr int gmap1[16] = {2,2,3,3,3,3,3,3,4,4,4,4,4,4,5,5};
        constexpr int gmap2[16] = {5,5,5,5,6,6,6,6,6,6,7,7,7,7,7,7};
        int gg = (ch == 0) ? gmap0[rl] : (ch == 1) ? gmap1[rl] : gmap2[rl];
        switch (gg) {                       // gg is compile-time (ch, rl unrolled)
          case 0: o0x += lo; o0y += hi; break;
          case 1: o1x += lo; o1y += hi; break;
          case 2: o2x += lo; o2y += hi; break;
          case 3: o3x += lo; o3y += hi; break;
          case 4: o4x += lo; o4y += hi; break;
          case 5: o5x += lo; o5y += hi; break;
          case 6: o6x += lo; o6y += hi; break;
          default: o7x += lo; o7y += hi; break;
        }
      }
      LDS_FENCE();                          // reads done before next chunk overwrites tb
    }
    // store 8 group rows: lane covers cols 2*lane, 2*lane+1
    size_t ob = (size_t)(job*8)*128 + lane*2;
    { float2 s = {o0x,o0y}; *(float2*)(out + ob + 0*128) = s; }
    { float2 s = {o1x,o1y}; *(float2*)(out + ob + 1*128) = s; }
    { float2 s = {o2x,o2y}; *(float2*)(out + ob + 2*128) = s; }
    { float2 s = {o3x,o3y}; *(float2*)(out + ob + 3*128) = s; }
    { float2 s = {o4x,o4y}; *(float2*)(out + ob + 4*128) = s; }
    { float2 s = {o5x,o5y}; *(float2*)(out + ob + 5*128) = s; }
    { float2 s = {o6x,o6y}; *(float2*)(out + ob + 6*128) = s; }
    { float2 s = {o7x,o7y}; *(float2*)(out + ob + 7*128) = s; }
  }
}

// ---------------- host launcher ----------------
extern "C" void kernel_launch(void* const* d_in, const int* in_sizes, int n_in,
                              void* d_out, int out_size, void* d_ws, size_t ws_size,
                              hipStream_t stream)
{
  const float* self_obs = (const float*)d_in[0];
  const float* obs  = (const float*)d_in[1];
  const float* e_w1 = (const float*)d_in[2];
  const float* e_b1 = (const float*)d_in[3];
  const float* e_w2 = (const float*)d_in[4];
  const float* e_b2 = (const float*)d_in[5];
  const float* v_w1 = (const float*)d_in[6];
  const float* v_b1 = (const float*)d_in[7];
  const float* v_w2 = (const float*)d_in[8];
  const float* v_b2 = (const float*)d_in[9];
  const float* a_w1 = (const float*)d_in[10];
  const float* a_b1 = (const float*)d_in[11];
  const float* a_w2 = (const float*)d_in[12];
  const float* a_b2 = (const float*)d_in[13];
  const float* a_w3 = (const float*)d_in[14];
  // a_b3 cancels in softmax — unused.

  f16*   wfrag = (f16*)d_ws;
  f16*   emb   = (f16*)((char*)d_ws + EMB_BYTE_OFF);
  f16*   perm  = (f16*)((char*)d_ws + PERM_BYTE_OFF);
  float* out   = (float*)d_out;

  prep_weights<<<400, 256, 0, stream>>>(e_w1, e_w2, v_w1, v_w2, a_w1, a_w2, wfrag);
  enc_kernel<<<683, 384, 0, stream>>>(self_obs, obs, e_b1, e_b2, a_b1, wfrag, emb, perm);
  att_kernel<<<256, 448, 0, stream>>>(wfrag, emb, perm, a_b2, a_w3, v_b1, v_b2, out);
}